// Round 6
// baseline (1719.395 us; speedup 1.0000x reference)
//
#include <hip/hip_runtime.h>

// ---------- 0: zero counters ----------
__global__ void k_init(int* deg, int* tmeta, int N){
  int i = blockIdx.x*blockDim.x + threadIdx.x;
  if (i < N) deg[i] = 0;
  if (i < 16) tmeta[i] = 0;
}

// ---------- 1: degree count (by dst) ----------
__global__ void k_count(const int* ei, int* deg, int N, int E){
  int i = blockIdx.x*blockDim.x + threadIdx.x;
  if (i < E) atomicAdd(&deg[ei[E + i]], 1);
}

// ---------- 2: exclusive scan (single block) ----------
__global__ __launch_bounds__(1024) void k_scan(const int* deg, int* off, int* cursor,
                                               int N, int E){
  __shared__ int sh[1024];
  int t = threadIdx.x;
  int chunk = (N + 1023) >> 10;
  int b0 = t * chunk; int b1 = min(b0 + chunk, N);
  int sum = 0;
  for (int i = b0; i < b1; ++i) sum += deg[i];
  sh[t] = sum;
  __syncthreads();
  for (int d = 1; d < 1024; d <<= 1){
    int v = (t >= d) ? sh[t - d] : 0;
    __syncthreads();
    sh[t] += v;
    __syncthreads();
  }
  int run = sh[t] - sum;  // exclusive prefix
  for (int i = b0; i < b1; ++i){
    off[i] = run; cursor[i] = run; run += deg[i];
  }
  if (t == 0) off[N] = E;
}

// ---------- 3: scatter edges into CSR ----------
__global__ void k_scatter(const int* ei, int* cursor, int* esrc, int E){
  int i = blockIdx.x*blockDim.x + threadIdx.x;
  if (i < E){
    int d = ei[E + i];
    int p = atomicAdd(&cursor[d], 1);
    esrc[p] = ei[i];
  }
}

// ---------- 5: h_sub / h_neigh projections: [N,8]@[8,64]+b (all f32) ----------
__global__ void k_h(const float* h_mat, const float* hsW, const float* hsb,
                    const float* hnW, const float* hnb,
                    float* hs, float* hn, int N){
  int i = blockIdx.x*blockDim.x + threadIdx.x;
  if (i >= N*64) return;
  int n = i >> 6, c = i & 63;
  float a0 = 0.f, a1 = 0.f;
  const float* hm = h_mat + (size_t)n*8;
  #pragma unroll
  for (int d = 0; d < 8; ++d){
    float hv = hm[d];
    a0 += hv * hsW[d*64 + c];
    a1 += hv * hnW[d*64 + c];
  }
  hs[i] = a0 + hsb[c];
  hn[i] = a1 + hnb[c];
}

// ---------- 6 DUMB: one thread per (n,o); direct W[t][d][o] reads ----------
__global__ void k_qk_dumb(const float* X, const float* subW, const float* neighW,
                          const float* subb, const float* neighb, const int* ntype,
                          float* q, float* k, int N){
  int i = blockIdx.x*blockDim.x + threadIdx.x;
  if (i >= N*128) return;
  int n = i >> 7, o = i & 127;
  int t = ntype[n];
  const float* x  = X + (size_t)n*128;
  const float* ws = subW   + (size_t)t*16384 + o;
  const float* wn = neighW + (size_t)t*16384 + o;
  float aq = 0.f, ak = 0.f;
  for (int d = 0; d < 128; ++d){
    float xv = x[d];
    aq += xv * ws[(size_t)d*128];
    ak += xv * wn[(size_t)d*128];
  }
  q[i] = aq + subb[t*128 + o];
  k[i] = ak + neighb[t*128 + o];
}

// ---------- 7 DUMB: one thread per (n,h); two-pass softmax; writes f32 aggr ----------
__global__ void k_edge_dumb(const float* q, const float* k, const float* hs, const float* hn,
                            const int* off, const int* esrc, const int* ntype,
                            const float* rel_att, const float* rel_h_att,
                            float* out, int N){
  int i = blockIdx.x*blockDim.x + threadIdx.x;
  if (i >= N*8) return;
  int n = i >> 3, h = i & 7;
  int st = ntype[n];
  const float* ra    = rel_att   + (size_t)(st*8 + h)*16;
  const float* rha   = rel_h_att + (size_t)(st*8 + h)*8;
  const float* qrow  = q  + (size_t)n*128 + h*16;
  const float* hsrow = hs + (size_t)n*64  + h*8;
  int e0 = off[n], e1 = off[n+1];
  // pass 1: segment max
  float m = -1e30f;
  for (int e = e0; e < e1; ++e){
    int sj = esrc[e];
    const float* krow  = k  + (size_t)sj*128 + h*16;
    const float* hnrow = hn + (size_t)sj*64  + h*8;
    float pp = 0.f;
    for (int j = 0; j < 16; ++j) pp += tanhf(qrow[j]*krow[j]) * ra[j];
    float ph = 0.f;
    for (int j = 0; j < 8;  ++j) ph += tanhf(hsrow[j]*hnrow[j]) * rha[j];
    float att = (pp*0.25f)*(ph*0.35355339059327373f);
    m = fmaxf(m, att);
  }
  // pass 2: denom + weighted aggregation of k_e
  float s = 0.f;
  float acc[16];
  #pragma unroll
  for (int j = 0; j < 16; ++j) acc[j] = 0.f;
  for (int e = e0; e < e1; ++e){
    int sj = esrc[e];
    const float* krow  = k  + (size_t)sj*128 + h*16;
    const float* hnrow = hn + (size_t)sj*64  + h*8;
    float pp = 0.f;
    for (int j = 0; j < 16; ++j) pp += tanhf(qrow[j]*krow[j]) * ra[j];
    float ph = 0.f;
    for (int j = 0; j < 8;  ++j) ph += tanhf(hsrow[j]*hnrow[j]) * rha[j];
    float att = (pp*0.25f)*(ph*0.35355339059327373f);
    float w = __expf(att - m);
    s += w;
    for (int j = 0; j < 16; ++j) acc[j] += w * krow[j];
  }
  float inv = 1.0f/(s + 1e-16f);
  float* orow = out + (size_t)n*128 + h*16;
  for (int j = 0; j < 16; ++j) orow[j] = acc[j]*inv;
}

// ---------- 8 DUMB: one thread per node; GELU + LayerNorm in-place (f32) ----------
__global__ void k_ln_dumb(const float* g, const float* be, float* out, int N){
  int n = blockIdx.x*blockDim.x + threadIdx.x;
  if (n >= N) return;
  float* row = out + (size_t)n*128;
  float v[128];
  float sm = 0.f;
  for (int j = 0; j < 128; ++j){
    float x = row[j];
    x = 0.5f*x*(1.f + erff(x*0.70710678118654752f));
    v[j] = x; sm += x;
  }
  float mu = sm * (1.f/128.f);
  float sq = 0.f;
  for (int j = 0; j < 128; ++j){ float d = v[j]-mu; sq += d*d; }
  float r = rsqrtf(sq*(1.f/128.f) + 1e-5f);
  for (int j = 0; j < 128; ++j)
    row[j] = (v[j]-mu)*r*g[j] + be[j];
}

extern "C" void kernel_launch(void* const* d_in, const int* in_sizes, int n_in,
                              void* d_out, int out_size, void* d_ws, size_t ws_size,
                              hipStream_t stream) {
  const float* meta_xs  = (const float*)d_in[0];
  const int*   node_type= (const int*)d_in[1];
  const int*   edge_idx = (const int*)d_in[2];
  const float* h_mat    = (const float*)d_in[3];
  const float* sub_W    = (const float*)d_in[4];
  const float* sub_b    = (const float*)d_in[5];
  const float* neigh_W  = (const float*)d_in[6];
  const float* neigh_b  = (const float*)d_in[7];
  const float* hsub_W   = (const float*)d_in[8];
  const float* hsub_b   = (const float*)d_in[9];
  const float* hneigh_W = (const float*)d_in[10];
  const float* hneigh_b = (const float*)d_in[11];
  const float* rel_att  = (const float*)d_in[12];
  const float* rel_hatt = (const float*)d_in[13];
  const float* ln_g     = (const float*)d_in[14];
  const float* ln_b     = (const float*)d_in[15];

  const int N = in_sizes[0] / 128;
  const int E = in_sizes[2] / 2;

  char* wbase = (char*)d_ws;
  size_t o = 0;
  auto carve = [&](size_t bytes)->char* {
    char* p = wbase + o;
    o = (o + bytes + 255) & ~(size_t)255;
    return p;
  };
  float* q      = (float*)carve((size_t)N*128*4);
  float* k      = (float*)carve((size_t)N*128*4);
  float* hs     = (float*)carve((size_t)N*64*4);
  float* hn     = (float*)carve((size_t)N*64*4);
  int*   off    = (int*)carve((size_t)(N+1)*4);
  int*   cursor = (int*)carve((size_t)N*4);
  int*   deg    = (int*)carve((size_t)N*4);
  int*   esrc   = (int*)carve((size_t)E*4);
  int*   tmeta  = (int*)carve(64);
  if (o > ws_size) return;

  k_init    <<<(N+255)/256, 256, 0, stream>>>(deg, tmeta, N);
  k_count   <<<(E+255)/256, 256, 0, stream>>>(edge_idx, deg, N, E);
  k_scan    <<<1, 1024, 0, stream>>>(deg, off, cursor, N, E);
  k_scatter <<<(E+255)/256, 256, 0, stream>>>(edge_idx, cursor, esrc, E);
  k_h       <<<((size_t)N*64+255)/256, 256, 0, stream>>>(h_mat, hsub_W, hsub_b,
                                                         hneigh_W, hneigh_b, hs, hn, N);
  k_qk_dumb <<<((size_t)N*128+255)/256, 256, 0, stream>>>(meta_xs, sub_W, neigh_W,
                                                          sub_b, neigh_b, node_type, q, k, N);
  k_edge_dumb<<<((size_t)N*8+255)/256, 256, 0, stream>>>(q, k, hs, hn, off, esrc, node_type,
                                                         rel_att, rel_hatt,
                                                         (float*)d_out, N);
  k_ln_dumb <<<(N+255)/256, 256, 0, stream>>>(ln_g, ln_b, (float*)d_out, N);
}

// Round 7
// 1221.702 us; speedup vs baseline: 1.4074x; 1.4074x over previous
//
#include <hip/hip_runtime.h>

__device__ __forceinline__ float tanh_fast(float x){
  float xc = fminf(fmaxf(x, -15.f), 15.f);       // tanh saturates; keeps exp finite
  float e = __expf(2.0f * xc);
  return 1.0f - 2.0f / (e + 1.0f);
}

// ---------- 0: zero counters ----------
__global__ void k_init(int* deg, int* tmeta, int N){
  int i = blockIdx.x*blockDim.x + threadIdx.x;
  if (i < N) deg[i] = 0;
  if (i < 16) tmeta[i] = 0;
}

// ---------- 1: degree count (by dst) + type histogram ----------
__global__ void k_count(const int* ei, const int* ntype, int* deg, int* tcnt, int N, int E){
  int i = blockIdx.x*blockDim.x + threadIdx.x;
  if (i < E) atomicAdd(&deg[ei[E + i]], 1);
  if (i < N) atomicAdd(&tcnt[ntype[i]], 1);
}

// ---------- 2: exclusive scan (single block) ----------
__global__ __launch_bounds__(1024) void k_scan(const int* deg, int* off, int* cursor,
                                               const int* tcnt, int* toff, int* tcur,
                                               int N, int E){
  __shared__ int sh[1024];
  int t = threadIdx.x;
  int chunk = (N + 1023) >> 10;
  int b0 = t * chunk; int b1 = min(b0 + chunk, N);
  int sum = 0;
  for (int i = b0; i < b1; ++i) sum += deg[i];
  sh[t] = sum;
  __syncthreads();
  for (int d = 1; d < 1024; d <<= 1){
    int v = (t >= d) ? sh[t - d] : 0;
    __syncthreads();
    sh[t] += v;
    __syncthreads();
  }
  int run = sh[t] - sum;
  for (int i = b0; i < b1; ++i){
    off[i] = run; cursor[i] = run; run += deg[i];
  }
  if (t == 0){
    off[N] = E;
    int a = 0; toff[0] = 0;
    for (int k = 0; k < 4; ++k){ a += tcnt[k]; toff[k+1] = a; }
    for (int k = 0; k < 4; ++k) tcur[k] = toff[k];
  }
}

// ---------- 3: scatter edges into CSR; nodes into type buckets ----------
__global__ void k_scatter(const int* ei, const int* ntype, int* cursor, int* tcur,
                          int* esrc, int* nbt, int N, int E){
  int i = blockIdx.x*blockDim.x + threadIdx.x;
  if (i < E){
    int d = ei[E + i];
    int p = atomicAdd(&cursor[d], 1);
    esrc[p] = ei[i];
  }
  if (i < N){
    int tt = ntype[i];
    int p = atomicAdd(&tcur[tt], 1);
    nbt[p] = i;
  }
}

// ---------- 4: transpose W[t][k][o] -> Wt[t][o][k], f32 ----------
__global__ void k_wt(const float* sub_W, const float* neigh_W,
                     float* wts, float* wtn){
  int i = blockIdx.x*blockDim.x + threadIdx.x;
  int w = i >> 16;
  int r = i & 65535;
  int t = r >> 14;
  int rem = r & 16383;
  int o = rem >> 7;
  int kd = rem & 127;
  const float* src = w ? neigh_W : sub_W;
  float* dstp = w ? wtn : wts;
  dstp[(t << 14) + (o << 7) + kd] = src[(t << 14) + (kd << 7) + o];
}

// ---------- 5: h_sub / h_neigh projections: [N,8]@[8,64]+b ----------
__global__ void k_h(const float* h_mat, const float* hsW, const float* hsb,
                    const float* hnW, const float* hnb,
                    float* hs, float* hn, int N){
  int i = blockIdx.x*blockDim.x + threadIdx.x;
  if (i >= N*64) return;
  int n = i >> 6, c = i & 63;
  float a0 = 0.f, a1 = 0.f;
  const float* hm = h_mat + (size_t)n*8;
  #pragma unroll
  for (int d = 0; d < 8; ++d){
    float hv = hm[d];
    a0 += hv * hsW[d*64 + c];
    a1 += hv * hnW[d*64 + c];
  }
  hs[i] = a0 + hsb[c];
  hn[i] = a1 + hnb[c];
}

// ---------- 6: type-selected projections, f32 VALU tiled GEMM ----------
// Block: 256 threads, 16 same-type nodes; X tile in LDS (broadcast reads).
// wave wv owns nodes wv*4..+3; c=tid&63 owns 4 output cols (0..127 q, 128..255 k).
__global__ __launch_bounds__(256) void k_qk_valu(const float* X,
      const float* wts, const float* wtn,
      const float* sub_b, const float* neigh_b,
      const int* nbt, const int* toff,
      float* q, float* k){
  int b = blockIdx.x;
  int t = -1, chunk = 0, acc0 = 0;
  #pragma unroll
  for (int tt = 0; tt < 4; ++tt){
    int cnt = toff[tt+1] - toff[tt];
    int nc = (cnt + 15) >> 4;
    if (t < 0 && b < acc0 + nc){ t = tt; chunk = b - acc0; }
    acc0 += nc;
  }
  if (t < 0) return;
  int base = toff[t] + chunk*16;
  int endp = toff[t+1];

  __shared__ float xs[16][128];
  {
    int nload = threadIdx.x >> 4;
    int doff  = (threadIdx.x & 15) * 8;
    int pL = base + nload;
    int nidL = nbt[pL < endp ? pL : toff[t]];
    const float* xp = X + (size_t)nidL*128 + doff;
    *reinterpret_cast<float4*>(&xs[nload][doff])     = *reinterpret_cast<const float4*>(xp);
    *reinterpret_cast<float4*>(&xs[nload][doff + 4]) = *reinterpret_cast<const float4*>(xp + 4);
  }
  __syncthreads();

  int wv = threadIdx.x >> 6;
  int c  = threadIdx.x & 63;
  int colbase = c * 4;
  bool isK = colbase >= 128;
  int ob = isK ? (colbase - 128) : colbase;
  const float* Wp   = (isK ? wtn : wts) + ((size_t)t << 14) + (size_t)ob * 128;
  const float* bias = (isK ? neigh_b : sub_b) + t * 128 + ob;
  float* outp = isK ? k : q;

  float acc[4][4];
  #pragma unroll
  for (int i = 0; i < 4; ++i)
    #pragma unroll
    for (int j = 0; j < 4; ++j) acc[i][j] = 0.f;

  for (int d = 0; d < 128; d += 4){
    float4 w0 = *reinterpret_cast<const float4*>(Wp + 0*128 + d);
    float4 w1 = *reinterpret_cast<const float4*>(Wp + 1*128 + d);
    float4 w2 = *reinterpret_cast<const float4*>(Wp + 2*128 + d);
    float4 w3 = *reinterpret_cast<const float4*>(Wp + 3*128 + d);
    #pragma unroll
    for (int nn = 0; nn < 4; ++nn){
      float4 xv = *reinterpret_cast<const float4*>(&xs[wv*4 + nn][d]);
      acc[nn][0] += xv.x*w0.x + xv.y*w0.y + xv.z*w0.z + xv.w*w0.w;
      acc[nn][1] += xv.x*w1.x + xv.y*w1.y + xv.z*w1.z + xv.w*w1.w;
      acc[nn][2] += xv.x*w2.x + xv.y*w2.y + xv.z*w2.z + xv.w*w2.w;
      acc[nn][3] += xv.x*w3.x + xv.y*w3.y + xv.z*w3.z + xv.w*w3.w;
    }
  }

  float b0 = bias[0], b1 = bias[1], b2 = bias[2], b3 = bias[3];
  #pragma unroll
  for (int nn = 0; nn < 4; ++nn){
    int pp = base + wv*4 + nn;
    if (pp < endp){
      int nid2 = nbt[pp];
      float4 o4 = make_float4(acc[nn][0] + b0, acc[nn][1] + b1,
                              acc[nn][2] + b2, acc[nn][3] + b3);
      *reinterpret_cast<float4*>(outp + (size_t)nid2*128 + ob) = o4;
    }
  }
}

// ---------- 7: per-dst-node wave: online softmax + aggregation + GELU + LayerNorm (f32 out) ----------
__global__ __launch_bounds__(256) void k_edge(const float* q, const float* k,
      const float* hs, const float* hn,
      const int* off, const int* esrc, const int* ntype,
      const float* rel_att, const float* rel_h_att,
      const float* ln_g, const float* ln_b,
      float* out, int N){
  int wid = (blockIdx.x*blockDim.x + threadIdx.x) >> 6;
  if (wid >= N) return;
  int lane = threadIdx.x & 63;
  int h = lane >> 3, t8 = lane & 7;
  const float2 qv = *reinterpret_cast<const float2*>(q + (size_t)wid*128 + lane*2);
  float hsv = hs[(size_t)wid*64 + lane];
  int st = ntype[wid];
  int rb = st*8 + h;
  float ra0 = rel_att[rb*16 + t8*2];
  float ra1 = rel_att[rb*16 + t8*2 + 1];
  float rha = rel_h_att[rb*8 + t8];
  float m = -1e30f, s = 0.f, a0 = 0.f, a1 = 0.f;
  int e0 = off[wid], e1 = off[wid+1];
  for (int e = e0; e < e1; ++e){
    int sj = esrc[e];
    float2 kv = *reinterpret_cast<const float2*>(k + (size_t)sj*128 + lane*2);
    float hnv = hn[(size_t)sj*64 + lane];
    float pp = tanh_fast(qv.x*kv.x)*ra0 + tanh_fast(qv.y*kv.y)*ra1;
    float ph = tanh_fast(hsv*hnv)*rha;
    pp += __shfl_xor(pp, 1); pp += __shfl_xor(pp, 2); pp += __shfl_xor(pp, 4);
    ph += __shfl_xor(ph, 1); ph += __shfl_xor(ph, 2); ph += __shfl_xor(ph, 4);
    float att = (pp * 0.25f) * (ph * 0.35355339059327373f);  // /sqrt(16) * /sqrt(8)
    float mn = fmaxf(m, att);
    float sc = __expf(m - mn);
    float ww = __expf(att - mn);
    s = s*sc + ww;
    a0 = a0*sc + ww*kv.x;
    a1 = a1*sc + ww*kv.y;
    m = mn;
  }
  float inv = 1.0f / (s + 1e-16f);
  float x0 = a0*inv, x1 = a1*inv;
  // exact GELU
  x0 = 0.5f * x0 * (1.f + erff(x0 * 0.70710678118654752f));
  x1 = 0.5f * x1 * (1.f + erff(x1 * 0.70710678118654752f));
  // LayerNorm across the wave (128 values, 2/lane)
  float sm = x0 + x1, sq = x0*x0 + x1*x1;
  #pragma unroll
  for (int d = 1; d < 64; d <<= 1){ sm += __shfl_xor(sm, d); sq += __shfl_xor(sq, d); }
  float mu = sm * (1.f/128.f);
  float var = fmaxf(sq * (1.f/128.f) - mu*mu, 0.f);
  float r = rsqrtf(var + 1e-5f);
  float g0 = ln_g[lane*2],  g1 = ln_g[lane*2+1];
  float be0 = ln_b[lane*2], be1 = ln_b[lane*2+1];
  float2 o2 = make_float2((x0 - mu)*r*g0 + be0, (x1 - mu)*r*g1 + be1);
  *reinterpret_cast<float2*>(out + (size_t)wid*128 + lane*2) = o2;
}

extern "C" void kernel_launch(void* const* d_in, const int* in_sizes, int n_in,
                              void* d_out, int out_size, void* d_ws, size_t ws_size,
                              hipStream_t stream) {
  const float* meta_xs  = (const float*)d_in[0];
  const int*   node_type= (const int*)d_in[1];
  const int*   edge_idx = (const int*)d_in[2];
  const float* h_mat    = (const float*)d_in[3];
  const float* sub_W    = (const float*)d_in[4];
  const float* sub_b    = (const float*)d_in[5];
  const float* neigh_W  = (const float*)d_in[6];
  const float* neigh_b  = (const float*)d_in[7];
  const float* hsub_W   = (const float*)d_in[8];
  const float* hsub_b   = (const float*)d_in[9];
  const float* hneigh_W = (const float*)d_in[10];
  const float* hneigh_b = (const float*)d_in[11];
  const float* rel_att  = (const float*)d_in[12];
  const float* rel_hatt = (const float*)d_in[13];
  const float* ln_g     = (const float*)d_in[14];
  const float* ln_b     = (const float*)d_in[15];

  const int N = in_sizes[0] / 128;
  const int E = in_sizes[2] / 2;

  char* wbase = (char*)d_ws;
  size_t o = 0;
  auto carve = [&](size_t bytes)->char* {
    char* p = wbase + o;
    o = (o + bytes + 255) & ~(size_t)255;
    return p;
  };
  float* q      = (float*)carve((size_t)N*128*4);
  float* k      = (float*)carve((size_t)N*128*4);
  float* hs     = (float*)carve((size_t)N*64*4);
  float* hn     = (float*)carve((size_t)N*64*4);
  int*   off    = (int*)carve((size_t)(N+1)*4);
  int*   cursor = (int*)carve((size_t)N*4);
  int*   deg    = (int*)carve((size_t)N*4);
  int*   esrc   = (int*)carve((size_t)E*4);
  int*   nbt    = (int*)carve((size_t)N*4);
  int*   tmeta  = (int*)carve(64);
  float* wts    = (float*)carve((size_t)4*128*128*4);
  float* wtn    = (float*)carve((size_t)4*128*128*4);
  if (o > ws_size) return;

  int* tcnt = tmeta;
  int* toff = tmeta + 4;
  int* tcur = tmeta + 9;

  const int M = (E > N) ? E : N;

  k_init   <<<(N+255)/256, 256, 0, stream>>>(deg, tmeta, N);
  k_count  <<<(M+255)/256, 256, 0, stream>>>(edge_idx, node_type, deg, tcnt, N, E);
  k_scan   <<<1, 1024, 0, stream>>>(deg, off, cursor, tcnt, toff, tcur, N, E);
  k_scatter<<<(M+255)/256, 256, 0, stream>>>(edge_idx, node_type, cursor, tcur, esrc, nbt, N, E);
  k_wt     <<<512, 256, 0, stream>>>(sub_W, neigh_W, wts, wtn);
  k_h      <<<((size_t)N*64+255)/256, 256, 0, stream>>>(h_mat, hsub_W, hsub_b,
                                                        hneigh_W, hneigh_b, hs, hn, N);
  k_qk_valu<<<((N+15)>>4)+4, 256, 0, stream>>>(meta_xs, wts, wtn, sub_b, neigh_b, nbt, toff, q, k);
  k_edge   <<<(N+3)/4, 256, 0, stream>>>(q, k, hs, hn, off, esrc, node_type,
                                         rel_att, rel_hatt, ln_g, ln_b,
                                         (float*)d_out, N);
}

// Round 8
// 638.280 us; speedup vs baseline: 2.6938x; 1.9141x over previous
//
#include <hip/hip_runtime.h>

__device__ __forceinline__ float tanh_fast(float x){
  float xc = fminf(fmaxf(x, -15.f), 15.f);
  float e = __expf(2.0f * xc);
  return 1.0f - 2.0f / (e + 1.0f);
}

// ---------- 0: head = -1, tmeta = 0 ----------
__global__ void k_init(int* head, int* tmeta, int N){
  int i = blockIdx.x*blockDim.x + threadIdx.x;
  if (i < N) head[i] = -1;
  if (i < 16) tmeta[i] = 0;
}

// ---------- 1: per-type node counts (wave-aggregated atomics: 4 per wave) ----------
__global__ void k_tc(const int* ntype, int* tcnt, int N){
  int i = blockIdx.x*blockDim.x + threadIdx.x;
  if (i >= N) return;
  int lane = threadIdx.x & 63;
  int myt = ntype[i];
  #pragma unroll
  for (int tt = 0; tt < 4; ++tt){
    unsigned long long mask = __ballot(myt == tt);
    if (mask){
      int leader = __ffsll((long long)mask) - 1;
      if (lane == leader) atomicAdd(&tcnt[tt], __popcll(mask));
    }
  }
}

// ---------- 2: tiny scan of 4 type counts ----------
__global__ void k_toff(const int* tcnt, int* toff, int* tcur){
  if (threadIdx.x == 0){
    int a = 0; toff[0] = 0;
    for (int k = 0; k < 4; ++k){ a += tcnt[k]; toff[k+1] = a; }
    for (int k = 0; k < 4; ++k) tcur[k] = toff[k];
  }
}

// ---------- 3: nodes into type buckets (ballot-aggregated) ----------
__global__ void k_nbt(const int* ntype, int* tcur, int* nbt, int N){
  int i = blockIdx.x*blockDim.x + threadIdx.x;
  if (i >= N) return;
  int lane = threadIdx.x & 63;
  int myt = ntype[i];
  unsigned long long below = (lane == 0) ? 0ull : ((~0ull) >> (64 - lane));
  #pragma unroll
  for (int tt = 0; tt < 4; ++tt){
    unsigned long long mask = __ballot(myt == tt);
    if (mask){
      int leader = __ffsll((long long)mask) - 1;
      int base = 0;
      if (lane == leader) base = atomicAdd(&tcur[tt], __popcll(mask));
      base = __shfl(base, leader);
      if (myt == tt){
        int pos = base + __popcll(mask & below);
        nbt[pos] = i;
      }
    }
  }
}

// ---------- 4: linked-list CSR: 1 random atomic + 1 coalesced write per edge ----------
__global__ void k_ll(const int* ei, int* head, int* nxt, int E){
  int i = blockIdx.x*blockDim.x + threadIdx.x;
  if (i < E){
    int d = ei[E + i];
    int old = atomicExch(&head[d], i);
    nxt[i] = old;
  }
}

// ---------- 5: transpose W[t][k][o] -> Wt[t][o][k], f32 ----------
__global__ void k_wt(const float* sub_W, const float* neigh_W,
                     float* wts, float* wtn){
  int i = blockIdx.x*blockDim.x + threadIdx.x;
  int w = i >> 16;
  int r = i & 65535;
  int t = r >> 14;
  int rem = r & 16383;
  int o = rem >> 7;
  int kd = rem & 127;
  const float* src = w ? neigh_W : sub_W;
  float* dstp = w ? wtn : wts;
  dstp[(t << 14) + (o << 7) + kd] = src[(t << 14) + (kd << 7) + o];
}

// ---------- 6: h_sub / h_neigh projections: [N,8]@[8,64]+b ----------
__global__ void k_h(const float* h_mat, const float* hsW, const float* hsb,
                    const float* hnW, const float* hnb,
                    float* hs, float* hn, int N){
  int i = blockIdx.x*blockDim.x + threadIdx.x;
  if (i >= N*64) return;
  int n = i >> 6, c = i & 63;
  float a0 = 0.f, a1 = 0.f;
  const float* hm = h_mat + (size_t)n*8;
  #pragma unroll
  for (int d = 0; d < 8; ++d){
    float hv = hm[d];
    a0 += hv * hsW[d*64 + c];
    a1 += hv * hnW[d*64 + c];
  }
  hs[i] = a0 + hsb[c];
  hn[i] = a1 + hnb[c];
}

// ---------- 7: type-selected projections, f32 VALU tiled GEMM ----------
__global__ __launch_bounds__(256) void k_qk_valu(const float* X,
      const float* wts, const float* wtn,
      const float* sub_b, const float* neigh_b,
      const int* nbt, const int* toff,
      float* q, float* k){
  int b = blockIdx.x;
  int t = -1, chunk = 0, acc0 = 0;
  #pragma unroll
  for (int tt = 0; tt < 4; ++tt){
    int cnt = toff[tt+1] - toff[tt];
    int nc = (cnt + 15) >> 4;
    if (t < 0 && b < acc0 + nc){ t = tt; chunk = b - acc0; }
    acc0 += nc;
  }
  if (t < 0) return;
  int base = toff[t] + chunk*16;
  int endp = toff[t+1];

  __shared__ float xs[16][128];
  {
    int nload = threadIdx.x >> 4;
    int doff  = (threadIdx.x & 15) * 8;
    int pL = base + nload;
    int nidL = nbt[pL < endp ? pL : toff[t]];
    const float* xp = X + (size_t)nidL*128 + doff;
    *reinterpret_cast<float4*>(&xs[nload][doff])     = *reinterpret_cast<const float4*>(xp);
    *reinterpret_cast<float4*>(&xs[nload][doff + 4]) = *reinterpret_cast<const float4*>(xp + 4);
  }
  __syncthreads();

  int wv = threadIdx.x >> 6;
  int c  = threadIdx.x & 63;
  int colbase = c * 4;
  bool isK = colbase >= 128;
  int ob = isK ? (colbase - 128) : colbase;
  const float* Wp   = (isK ? wtn : wts) + ((size_t)t << 14) + (size_t)ob * 128;
  const float* bias = (isK ? neigh_b : sub_b) + t * 128 + ob;
  float* outp = isK ? k : q;

  float acc[4][4];
  #pragma unroll
  for (int i = 0; i < 4; ++i)
    #pragma unroll
    for (int j = 0; j < 4; ++j) acc[i][j] = 0.f;

  for (int d = 0; d < 128; d += 4){
    float4 w0 = *reinterpret_cast<const float4*>(Wp + 0*128 + d);
    float4 w1 = *reinterpret_cast<const float4*>(Wp + 1*128 + d);
    float4 w2 = *reinterpret_cast<const float4*>(Wp + 2*128 + d);
    float4 w3 = *reinterpret_cast<const float4*>(Wp + 3*128 + d);
    #pragma unroll
    for (int nn = 0; nn < 4; ++nn){
      float4 xv = *reinterpret_cast<const float4*>(&xs[wv*4 + nn][d]);
      acc[nn][0] += xv.x*w0.x + xv.y*w0.y + xv.z*w0.z + xv.w*w0.w;
      acc[nn][1] += xv.x*w1.x + xv.y*w1.y + xv.z*w1.z + xv.w*w1.w;
      acc[nn][2] += xv.x*w2.x + xv.y*w2.y + xv.z*w2.z + xv.w*w2.w;
      acc[nn][3] += xv.x*w3.x + xv.y*w3.y + xv.z*w3.z + xv.w*w3.w;
    }
  }

  float b0 = bias[0], b1 = bias[1], b2 = bias[2], b3 = bias[3];
  #pragma unroll
  for (int nn = 0; nn < 4; ++nn){
    int pp = base + wv*4 + nn;
    if (pp < endp){
      int nid2 = nbt[pp];
      float4 o4 = make_float4(acc[nn][0] + b0, acc[nn][1] + b1,
                              acc[nn][2] + b2, acc[nn][3] + b3);
      *reinterpret_cast<float4*>(outp + (size_t)nid2*128 + ob) = o4;
    }
  }
}

// ---------- 8: per-dst-node wave: LL walk + online softmax + GELU + LayerNorm ----------
__global__ __launch_bounds__(256) void k_edge(const float* q, const float* k,
      const float* hs, const float* hn,
      const int* head, const int* nxt, const int* ei,
      const int* ntype,
      const float* rel_att, const float* rel_h_att,
      const float* ln_g, const float* ln_b,
      float* out, int N){
  int wid = (blockIdx.x*blockDim.x + threadIdx.x) >> 6;
  if (wid >= N) return;
  int lane = threadIdx.x & 63;
  int h = lane >> 3, t8 = lane & 7;
  const float2 qv = *reinterpret_cast<const float2*>(q + (size_t)wid*128 + lane*2);
  float hsv = hs[(size_t)wid*64 + lane];
  int st = ntype[wid];
  int rb = st*8 + h;
  float ra0 = rel_att[rb*16 + t8*2];
  float ra1 = rel_att[rb*16 + t8*2 + 1];
  float rha = rel_h_att[rb*8 + t8];
  float m = -1e30f, s = 0.f, a0 = 0.f, a1 = 0.f;
  int e = head[wid];
  while (e >= 0){
    int en = nxt[e];          // prefetch next link (broadcast load)
    int sj = ei[e];           // src node id (broadcast load)
    float2 kv = *reinterpret_cast<const float2*>(k + (size_t)sj*128 + lane*2);
    float hnv = hn[(size_t)sj*64 + lane];
    float pp = tanh_fast(qv.x*kv.x)*ra0 + tanh_fast(qv.y*kv.y)*ra1;
    float ph = tanh_fast(hsv*hnv)*rha;
    pp += __shfl_xor(pp, 1); pp += __shfl_xor(pp, 2); pp += __shfl_xor(pp, 4);
    ph += __shfl_xor(ph, 1); ph += __shfl_xor(ph, 2); ph += __shfl_xor(ph, 4);
    float att = (pp * 0.25f) * (ph * 0.35355339059327373f);
    float mn = fmaxf(m, att);
    float sc = __expf(m - mn);
    float ww = __expf(att - mn);
    s = s*sc + ww;
    a0 = a0*sc + ww*kv.x;
    a1 = a1*sc + ww*kv.y;
    m = mn;
    e = en;
  }
  float inv = 1.0f / (s + 1e-16f);
  float x0 = a0*inv, x1 = a1*inv;
  x0 = 0.5f * x0 * (1.f + erff(x0 * 0.70710678118654752f));
  x1 = 0.5f * x1 * (1.f + erff(x1 * 0.70710678118654752f));
  float sm = x0 + x1, sq = x0*x0 + x1*x1;
  #pragma unroll
  for (int d = 1; d < 64; d <<= 1){ sm += __shfl_xor(sm, d); sq += __shfl_xor(sq, d); }
  float mu = sm * (1.f/128.f);
  float var = fmaxf(sq * (1.f/128.f) - mu*mu, 0.f);
  float r = rsqrtf(var + 1e-5f);
  float g0 = ln_g[lane*2],  g1 = ln_g[lane*2+1];
  float be0 = ln_b[lane*2], be1 = ln_b[lane*2+1];
  float2 o2 = make_float2((x0 - mu)*r*g0 + be0, (x1 - mu)*r*g1 + be1);
  *reinterpret_cast<float2*>(out + (size_t)wid*128 + lane*2) = o2;
}

extern "C" void kernel_launch(void* const* d_in, const int* in_sizes, int n_in,
                              void* d_out, int out_size, void* d_ws, size_t ws_size,
                              hipStream_t stream) {
  const float* meta_xs  = (const float*)d_in[0];
  const int*   node_type= (const int*)d_in[1];
  const int*   edge_idx = (const int*)d_in[2];
  const float* h_mat    = (const float*)d_in[3];
  const float* sub_W    = (const float*)d_in[4];
  const float* sub_b    = (const float*)d_in[5];
  const float* neigh_W  = (const float*)d_in[6];
  const float* neigh_b  = (const float*)d_in[7];
  const float* hsub_W   = (const float*)d_in[8];
  const float* hsub_b   = (const float*)d_in[9];
  const float* hneigh_W = (const float*)d_in[10];
  const float* hneigh_b = (const float*)d_in[11];
  const float* rel_att  = (const float*)d_in[12];
  const float* rel_hatt = (const float*)d_in[13];
  const float* ln_g     = (const float*)d_in[14];
  const float* ln_b     = (const float*)d_in[15];

  const int N = in_sizes[0] / 128;
  const int E = in_sizes[2] / 2;

  char* wbase = (char*)d_ws;
  size_t o = 0;
  auto carve = [&](size_t bytes)->char* {
    char* p = wbase + o;
    o = (o + bytes + 255) & ~(size_t)255;
    return p;
  };
  float* q      = (float*)carve((size_t)N*128*4);
  float* k      = (float*)carve((size_t)N*128*4);
  float* hs     = (float*)carve((size_t)N*64*4);
  float* hn     = (float*)carve((size_t)N*64*4);
  int*   head   = (int*)carve((size_t)N*4);
  int*   nxt    = (int*)carve((size_t)E*4);
  int*   nbt    = (int*)carve((size_t)N*4);
  int*   tmeta  = (int*)carve(64);
  float* wts    = (float*)carve((size_t)4*128*128*4);
  float* wtn    = (float*)carve((size_t)4*128*128*4);
  if (o > ws_size) return;

  int* tcnt = tmeta;
  int* toff = tmeta + 4;
  int* tcur = tmeta + 9;

  k_init   <<<(N+255)/256, 256, 0, stream>>>(head, tmeta, N);
  k_tc     <<<(N+255)/256, 256, 0, stream>>>(node_type, tcnt, N);
  k_toff   <<<1, 64, 0, stream>>>(tcnt, toff, tcur);
  k_nbt    <<<(N+255)/256, 256, 0, stream>>>(node_type, tcur, nbt, N);
  k_ll     <<<(E+255)/256, 256, 0, stream>>>(edge_idx, head, nxt, E);
  k_wt     <<<512, 256, 0, stream>>>(sub_W, neigh_W, wts, wtn);
  k_h      <<<((size_t)N*64+255)/256, 256, 0, stream>>>(h_mat, hsub_W, hsub_b,
                                                        hneigh_W, hneigh_b, hs, hn, N);
  k_qk_valu<<<((N+15)>>4)+4, 256, 0, stream>>>(meta_xs, wts, wtn, sub_b, neigh_b, nbt, toff, q, k);
  k_edge   <<<(N+3)/4, 256, 0, stream>>>(q, k, hs, hn, head, nxt, edge_idx, node_type,
                                         rel_att, rel_hatt, ln_g, ln_b,
                                         (float*)d_out, N);
}

// Round 9
// 430.694 us; speedup vs baseline: 3.9921x; 1.4820x over previous
//
#include <hip/hip_runtime.h>

__device__ __forceinline__ float tanh_fast(float x){
  float xc = fminf(fmaxf(x, -15.f), 15.f);
  float e = __expf(2.0f * xc);
  return 1.0f - 2.0f / (e + 1.0f);
}
__device__ __forceinline__ void fma4(float4& a, float s, const float4& b){
  a.x = fmaf(s, b.x, a.x); a.y = fmaf(s, b.y, a.y);
  a.z = fmaf(s, b.z, a.z); a.w = fmaf(s, b.w, a.w);
}

// ---------- 0: head = -1, tmeta = 0 ----------
__global__ void k_init(int* head, int* tmeta, int N){
  int i = blockIdx.x*blockDim.x + threadIdx.x;
  if (i < N) head[i] = -1;
  if (i < 16) tmeta[i] = 0;
}

// ---------- 1: per-type node counts (wave-aggregated atomics) ----------
__global__ void k_tc(const int* ntype, int* tcnt, int N){
  int i = blockIdx.x*blockDim.x + threadIdx.x;
  if (i >= N) return;
  int lane = threadIdx.x & 63;
  int myt = ntype[i];
  #pragma unroll
  for (int tt = 0; tt < 4; ++tt){
    unsigned long long mask = __ballot(myt == tt);
    if (mask){
      int leader = __ffsll((long long)mask) - 1;
      if (lane == leader) atomicAdd(&tcnt[tt], __popcll(mask));
    }
  }
}

// ---------- 2: tiny scan of 4 type counts ----------
__global__ void k_toff(const int* tcnt, int* toff, int* tcur){
  if (threadIdx.x == 0){
    int a = 0; toff[0] = 0;
    for (int k = 0; k < 4; ++k){ a += tcnt[k]; toff[k+1] = a; }
    for (int k = 0; k < 4; ++k) tcur[k] = toff[k];
  }
}

// ---------- 3: nodes into type buckets (ballot-aggregated) ----------
__global__ void k_nbt(const int* ntype, int* tcur, int* nbt, int N){
  int i = blockIdx.x*blockDim.x + threadIdx.x;
  if (i >= N) return;
  int lane = threadIdx.x & 63;
  int myt = ntype[i];
  unsigned long long below = (lane == 0) ? 0ull : ((~0ull) >> (64 - lane));
  #pragma unroll
  for (int tt = 0; tt < 4; ++tt){
    unsigned long long mask = __ballot(myt == tt);
    if (mask){
      int leader = __ffsll((long long)mask) - 1;
      int base = 0;
      if (lane == leader) base = atomicAdd(&tcur[tt], __popcll(mask));
      base = __shfl(base, leader);
      if (myt == tt){
        int pos = base + __popcll(mask & below);
        nbt[pos] = i;
      }
    }
  }
}

// ---------- 4: linked-list CSR ----------
__global__ void k_ll(const int* ei, int* head, int* nxt, int E){
  int i = blockIdx.x*blockDim.x + threadIdx.x;
  if (i < E){
    int d = ei[E + i];
    int old = atomicExch(&head[d], i);
    nxt[i] = old;
  }
}

// ---------- 5: h_sub / h_neigh projections ----------
__global__ void k_h(const float* h_mat, const float* hsW, const float* hsb,
                    const float* hnW, const float* hnb,
                    float* hs, float* hn, int N){
  int i = blockIdx.x*blockDim.x + threadIdx.x;
  if (i >= N*64) return;
  int n = i >> 6, c = i & 63;
  float a0 = 0.f, a1 = 0.f;
  const float* hm = h_mat + (size_t)n*8;
  #pragma unroll
  for (int d = 0; d < 8; ++d){
    float hv = hm[d];
    a0 += hv * hsW[d*64 + c];
    a1 += hv * hnW[d*64 + c];
  }
  hs[i] = a0 + hsb[c];
  hn[i] = a1 + hnb[c];
}

// ---------- 6: type-selected projections, tiled f32 GEMM ----------
// Block = 64 nodes x 64 cols, K=128. grid.y: 0,1 -> q cols 0/64; 2,3 -> k cols 0/64.
// LDS: X tile node-major with XOR-swizzle (conflict-free 4-row reads),
//      W tile k-major (per-k col-reads conflict-free; loaded straight from W[t][k][o]).
__global__ __launch_bounds__(256) void k_qk_gemm(const float* X,
      const float* subW, const float* neighW,
      const float* sub_b, const float* neigh_b,
      const int* nbt, const int* toff,
      float* q, float* k){
  int b = blockIdx.x;
  int t = -1, chunk = 0, acc0 = 0;
  #pragma unroll
  for (int tt = 0; tt < 4; ++tt){
    int cnt = toff[tt+1] - toff[tt];
    int nc = (cnt + 63) >> 6;
    if (t < 0 && b < acc0 + nc){ t = tt; chunk = b - acc0; }
    acc0 += nc;
  }
  if (t < 0) return;
  int base = toff[t] + chunk*64;
  int endp = toff[t+1];
  int fallback = toff[t];

  bool isK = blockIdx.y >= 2;
  int c0 = (blockIdx.y & 1) * 64;
  const float* Wg   = (isK ? neighW : subW) + ((size_t)t << 14);   // [k][o] row-major
  const float* bias = (isK ? neigh_b : sub_b) + t*128 + c0;
  float* outp = isK ? k : q;

  __shared__ float xs[64*128];   // [node][phys_f4*4], swizzled
  __shared__ float wk[128*64];   // [k][col]

  int tid = threadIdx.x;
  // load X tile: 2048 float4, coalesced; swizzle phys_f4 = f4 ^ (((node>>2)&3)<<1)
  #pragma unroll
  for (int i = 0; i < 8; ++i){
    int f = tid + i*256;
    int node = f >> 5;
    int f4 = f & 31;
    int pp = base + node;
    int nid = nbt[pp < endp ? pp : fallback];
    float4 v = *reinterpret_cast<const float4*>(X + (size_t)nid*128 + f4*4);
    int phys = f4 ^ (((node >> 2) & 3) << 1);
    *reinterpret_cast<float4*>(&xs[node*128 + phys*4]) = v;
  }
  // load W tile: 2048 float4 from W[t][k][c0..c0+63], coalesced; store k-major
  #pragma unroll
  for (int i = 0; i < 8; ++i){
    int f = tid + i*256;
    int kk = f >> 4;            // 0..127
    int col = (f & 15) * 4;     // 0..60
    float4 v = *reinterpret_cast<const float4*>(Wg + (size_t)kk*128 + c0 + col);
    *reinterpret_cast<float4*>(&wk[kk*64 + col]) = v;
  }
  __syncthreads();

  int ty = tid >> 4;   // node group: nodes ty*4..+3
  int tx = tid & 15;   // col group:  cols  tx*4..+3
  float4 acc4[4] = {make_float4(0,0,0,0), make_float4(0,0,0,0),
                    make_float4(0,0,0,0), make_float4(0,0,0,0)};
  int xsw = (ty & 3) << 1;     // node>>2 == ty for nodes ty*4+i

  #pragma unroll 2
  for (int k4 = 0; k4 < 32; ++k4){
    int kb = k4 * 4;
    int physoff = (k4 ^ xsw) * 4;
    float4 xv0 = *reinterpret_cast<const float4*>(&xs[(ty*4+0)*128 + physoff]);
    float4 xv1 = *reinterpret_cast<const float4*>(&xs[(ty*4+1)*128 + physoff]);
    float4 xv2 = *reinterpret_cast<const float4*>(&xs[(ty*4+2)*128 + physoff]);
    float4 xv3 = *reinterpret_cast<const float4*>(&xs[(ty*4+3)*128 + physoff]);
    float4 wv0 = *reinterpret_cast<const float4*>(&wk[(kb+0)*64 + tx*4]);
    float4 wv1 = *reinterpret_cast<const float4*>(&wk[(kb+1)*64 + tx*4]);
    float4 wv2 = *reinterpret_cast<const float4*>(&wk[(kb+2)*64 + tx*4]);
    float4 wv3 = *reinterpret_cast<const float4*>(&wk[(kb+3)*64 + tx*4]);
    fma4(acc4[0], xv0.x, wv0); fma4(acc4[0], xv0.y, wv1); fma4(acc4[0], xv0.z, wv2); fma4(acc4[0], xv0.w, wv3);
    fma4(acc4[1], xv1.x, wv0); fma4(acc4[1], xv1.y, wv1); fma4(acc4[1], xv1.z, wv2); fma4(acc4[1], xv1.w, wv3);
    fma4(acc4[2], xv2.x, wv0); fma4(acc4[2], xv2.y, wv1); fma4(acc4[2], xv2.z, wv2); fma4(acc4[2], xv2.w, wv3);
    fma4(acc4[3], xv3.x, wv0); fma4(acc4[3], xv3.y, wv1); fma4(acc4[3], xv3.z, wv2); fma4(acc4[3], xv3.w, wv3);
  }

  float4 b4 = *reinterpret_cast<const float4*>(bias + tx*4);
  #pragma unroll
  for (int i = 0; i < 4; ++i){
    int pp = base + ty*4 + i;
    if (pp < endp){
      int nid = nbt[pp];
      float4 o4 = make_float4(acc4[i].x + b4.x, acc4[i].y + b4.y,
                              acc4[i].z + b4.z, acc4[i].w + b4.w);
      *reinterpret_cast<float4*>(outp + (size_t)nid*128 + c0 + tx*4) = o4;
    }
  }
}

// ---------- 7: per-dst-node wave: LL walk + online softmax + GELU + LayerNorm ----------
__global__ __launch_bounds__(256) void k_edge(const float* q, const float* k,
      const float* hs, const float* hn,
      const int* head, const int* nxt, const int* ei,
      const int* ntype,
      const float* rel_att, const float* rel_h_att,
      const float* ln_g, const float* ln_b,
      float* out, int N){
  int wid = (blockIdx.x*blockDim.x + threadIdx.x) >> 6;
  if (wid >= N) return;
  int lane = threadIdx.x & 63;
  int h = lane >> 3, t8 = lane & 7;
  const float2 qv = *reinterpret_cast<const float2*>(q + (size_t)wid*128 + lane*2);
  float hsv = hs[(size_t)wid*64 + lane];
  int st = ntype[wid];
  int rb = st*8 + h;
  float ra0 = rel_att[rb*16 + t8*2];
  float ra1 = rel_att[rb*16 + t8*2 + 1];
  float rha = rel_h_att[rb*8 + t8];
  float m = -1e30f, s = 0.f, a0 = 0.f, a1 = 0.f;
  int e = head[wid];
  while (e >= 0){
    int en = nxt[e];
    int sj = ei[e];
    float2 kv = *reinterpret_cast<const float2*>(k + (size_t)sj*128 + lane*2);
    float hnv = hn[(size_t)sj*64 + lane];
    float pp = tanh_fast(qv.x*kv.x)*ra0 + tanh_fast(qv.y*kv.y)*ra1;
    float ph = tanh_fast(hsv*hnv)*rha;
    pp += __shfl_xor(pp, 1); pp += __shfl_xor(pp, 2); pp += __shfl_xor(pp, 4);
    ph += __shfl_xor(ph, 1); ph += __shfl_xor(ph, 2); ph += __shfl_xor(ph, 4);
    float att = (pp * 0.25f) * (ph * 0.35355339059327373f);
    float mn = fmaxf(m, att);
    float sc = __expf(m - mn);
    float ww = __expf(att - mn);
    s = s*sc + ww;
    a0 = a0*sc + ww*kv.x;
    a1 = a1*sc + ww*kv.y;
    m = mn;
    e = en;
  }
  float inv = 1.0f / (s + 1e-16f);
  float x0 = a0*inv, x1 = a1*inv;
  x0 = 0.5f * x0 * (1.f + erff(x0 * 0.70710678118654752f));
  x1 = 0.5f * x1 * (1.f + erff(x1 * 0.70710678118654752f));
  float sm = x0 + x1, sq = x0*x0 + x1*x1;
  #pragma unroll
  for (int d = 1; d < 64; d <<= 1){ sm += __shfl_xor(sm, d); sq += __shfl_xor(sq, d); }
  float mu = sm * (1.f/128.f);
  float var = fmaxf(sq * (1.f/128.f) - mu*mu, 0.f);
  float r = rsqrtf(var + 1e-5f);
  float g0 = ln_g[lane*2],  g1 = ln_g[lane*2+1];
  float be0 = ln_b[lane*2], be1 = ln_b[lane*2+1];
  float2 o2 = make_float2((x0 - mu)*r*g0 + be0, (x1 - mu)*r*g1 + be1);
  *reinterpret_cast<float2*>(out + (size_t)wid*128 + lane*2) = o2;
}

extern "C" void kernel_launch(void* const* d_in, const int* in_sizes, int n_in,
                              void* d_out, int out_size, void* d_ws, size_t ws_size,
                              hipStream_t stream) {
  const float* meta_xs  = (const float*)d_in[0];
  const int*   node_type= (const int*)d_in[1];
  const int*   edge_idx = (const int*)d_in[2];
  const float* h_mat    = (const float*)d_in[3];
  const float* sub_W    = (const float*)d_in[4];
  const float* sub_b    = (const float*)d_in[5];
  const float* neigh_W  = (const float*)d_in[6];
  const float* neigh_b  = (const float*)d_in[7];
  const float* hsub_W   = (const float*)d_in[8];
  const float* hsub_b   = (const float*)d_in[9];
  const float* hneigh_W = (const float*)d_in[10];
  const float* hneigh_b = (const float*)d_in[11];
  const float* rel_att  = (const float*)d_in[12];
  const float* rel_hatt = (const float*)d_in[13];
  const float* ln_g     = (const float*)d_in[14];
  const float* ln_b     = (const float*)d_in[15];

  const int N = in_sizes[0] / 128;
  const int E = in_sizes[2] / 2;

  char* wbase = (char*)d_ws;
  size_t o = 0;
  auto carve = [&](size_t bytes)->char* {
    char* p = wbase + o;
    o = (o + bytes + 255) & ~(size_t)255;
    return p;
  };
  float* q      = (float*)carve((size_t)N*128*4);
  float* k      = (float*)carve((size_t)N*128*4);
  float* hs     = (float*)carve((size_t)N*64*4);
  float* hn     = (float*)carve((size_t)N*64*4);
  int*   head   = (int*)carve((size_t)N*4);
  int*   nxt    = (int*)carve((size_t)E*4);
  int*   nbt    = (int*)carve((size_t)N*4);
  int*   tmeta  = (int*)carve(64);
  if (o > ws_size) return;

  int* tcnt = tmeta;
  int* toff = tmeta + 4;
  int* tcur = tmeta + 9;

  k_init   <<<(N+255)/256, 256, 0, stream>>>(head, tmeta, N);
  k_tc     <<<(N+255)/256, 256, 0, stream>>>(node_type, tcnt, N);
  k_toff   <<<1, 64, 0, stream>>>(tcnt, toff, tcur);
  k_nbt    <<<(N+255)/256, 256, 0, stream>>>(node_type, tcur, nbt, N);
  k_ll     <<<(E+255)/256, 256, 0, stream>>>(edge_idx, head, nxt, E);
  k_h      <<<((size_t)N*64+255)/256, 256, 0, stream>>>(h_mat, hsub_W, hsub_b,
                                                        hneigh_W, hneigh_b, hs, hn, N);
  dim3 g_qk(((N + 63) >> 6) + 4, 4);
  k_qk_gemm<<<g_qk, 256, 0, stream>>>(meta_xs, sub_W, neigh_W, sub_b, neigh_b,
                                      nbt, toff, q, k);
  k_edge   <<<(N+3)/4, 256, 0, stream>>>(q, k, hs, hn, head, nxt, edge_idx, node_type,
                                         rel_att, rel_hatt, ln_g, ln_b,
                                         (float*)d_out, N);
}

// Round 10
// 406.949 us; speedup vs baseline: 4.2251x; 1.0583x over previous
//
#include <hip/hip_runtime.h>

// tanh(x) = 1 - 2/(e^{2x}+1); no clamp needed: exp->inf => rcp->0 => 1; exp->0 => -1.
__device__ __forceinline__ float tanh_fast(float x){
  float e = __expf(2.0f * x);
  return 1.0f - 2.0f * __builtin_amdgcn_rcpf(e + 1.0f);
}
template<int CTRL>
__device__ __forceinline__ float dpp_add(float x){
  union { float f; int i; } a, b;
  a.f = x;
  b.i = __builtin_amdgcn_mov_dpp(a.i, CTRL, 0xF, 0xF, true);
  return x + b.f;
}
// sum over each 8-lane group: lane^1, lane^2 (quad_perm), then cross-quad via row_half_mirror
__device__ __forceinline__ float sum8(float x){
  x = dpp_add<0xB1>(x);    // quad_perm [1,0,3,2]
  x = dpp_add<0x4E>(x);    // quad_perm [2,3,0,1]
  x = dpp_add<0x141>(x);   // row_half_mirror
  return x;
}
__device__ __forceinline__ void fma4(float4& a, float s, const float4& b){
  a.x = fmaf(s, b.x, a.x); a.y = fmaf(s, b.y, a.y);
  a.z = fmaf(s, b.z, a.z); a.w = fmaf(s, b.w, a.w);
}

// ---------- 0: head = -1, tmeta = 0 ----------
__global__ void k_init(int* head, int* tmeta, int N){
  int i = blockIdx.x*blockDim.x + threadIdx.x;
  if (i < N) head[i] = -1;
  if (i < 16) tmeta[i] = 0;
}

// ---------- 1: per-type node counts (wave-aggregated atomics) ----------
__global__ void k_tc(const int* ntype, int* tcnt, int N){
  int i = blockIdx.x*blockDim.x + threadIdx.x;
  if (i >= N) return;
  int lane = threadIdx.x & 63;
  int myt = ntype[i];
  #pragma unroll
  for (int tt = 0; tt < 4; ++tt){
    unsigned long long mask = __ballot(myt == tt);
    if (mask){
      int leader = __ffsll((long long)mask) - 1;
      if (lane == leader) atomicAdd(&tcnt[tt], __popcll(mask));
    }
  }
}

// ---------- 2: tiny scan of 4 type counts ----------
__global__ void k_toff(const int* tcnt, int* toff, int* tcur){
  if (threadIdx.x == 0){
    int a = 0; toff[0] = 0;
    for (int k = 0; k < 4; ++k){ a += tcnt[k]; toff[k+1] = a; }
    for (int k = 0; k < 4; ++k) tcur[k] = toff[k];
  }
}

// ---------- 3: nodes into type buckets (ballot-aggregated) ----------
__global__ void k_nbt(const int* ntype, int* tcur, int* nbt, int N){
  int i = blockIdx.x*blockDim.x + threadIdx.x;
  if (i >= N) return;
  int lane = threadIdx.x & 63;
  int myt = ntype[i];
  unsigned long long below = (lane == 0) ? 0ull : ((~0ull) >> (64 - lane));
  #pragma unroll
  for (int tt = 0; tt < 4; ++tt){
    unsigned long long mask = __ballot(myt == tt);
    if (mask){
      int leader = __ffsll((long long)mask) - 1;
      int base = 0;
      if (lane == leader) base = atomicAdd(&tcur[tt], __popcll(mask));
      base = __shfl(base, leader);
      if (myt == tt){
        int pos = base + __popcll(mask & below);
        nbt[pos] = i;
      }
    }
  }
}

// ---------- 4: linked-list CSR ----------
__global__ void k_ll(const int* ei, int* head, int* nxt, int E){
  int i = blockIdx.x*blockDim.x + threadIdx.x;
  if (i < E){
    int d = ei[E + i];
    int old = atomicExch(&head[d], i);
    nxt[i] = old;
  }
}

// ---------- 5: h_sub / h_neigh projections ----------
__global__ void k_h(const float* h_mat, const float* hsW, const float* hsb,
                    const float* hnW, const float* hnb,
                    float* hs, float* hn, int N){
  int i = blockIdx.x*blockDim.x + threadIdx.x;
  if (i >= N*64) return;
  int n = i >> 6, c = i & 63;
  float a0 = 0.f, a1 = 0.f;
  const float* hm = h_mat + (size_t)n*8;
  #pragma unroll
  for (int d = 0; d < 8; ++d){
    float hv = hm[d];
    a0 += hv * hsW[d*64 + c];
    a1 += hv * hnW[d*64 + c];
  }
  hs[i] = a0 + hsb[c];
  hn[i] = a1 + hnb[c];
}

// ---------- 6: type-selected projections, tiled f32 GEMM ----------
__global__ __launch_bounds__(256) void k_qk_gemm(const float* X,
      const float* subW, const float* neighW,
      const float* sub_b, const float* neigh_b,
      const int* nbt, const int* toff,
      float* q, float* k){
  int b = blockIdx.x;
  int t = -1, chunk = 0, acc0 = 0;
  #pragma unroll
  for (int tt = 0; tt < 4; ++tt){
    int cnt = toff[tt+1] - toff[tt];
    int nc = (cnt + 63) >> 6;
    if (t < 0 && b < acc0 + nc){ t = tt; chunk = b - acc0; }
    acc0 += nc;
  }
  if (t < 0) return;
  int base = toff[t] + chunk*64;
  int endp = toff[t+1];
  int fallback = toff[t];

  bool isK = blockIdx.y >= 2;
  int c0 = (blockIdx.y & 1) * 64;
  const float* Wg   = (isK ? neighW : subW) + ((size_t)t << 14);
  const float* bias = (isK ? neigh_b : sub_b) + t*128 + c0;
  float* outp = isK ? k : q;

  __shared__ float xs[64*128];
  __shared__ float wk[128*64];

  int tid = threadIdx.x;
  #pragma unroll
  for (int i = 0; i < 8; ++i){
    int f = tid + i*256;
    int node = f >> 5;
    int f4 = f & 31;
    int pp = base + node;
    int nid = nbt[pp < endp ? pp : fallback];
    float4 v = *reinterpret_cast<const float4*>(X + (size_t)nid*128 + f4*4);
    int phys = f4 ^ (((node >> 2) & 3) << 1);
    *reinterpret_cast<float4*>(&xs[node*128 + phys*4]) = v;
  }
  #pragma unroll
  for (int i = 0; i < 8; ++i){
    int f = tid + i*256;
    int kk = f >> 4;
    int col = (f & 15) * 4;
    float4 v = *reinterpret_cast<const float4*>(Wg + (size_t)kk*128 + c0 + col);
    *reinterpret_cast<float4*>(&wk[kk*64 + col]) = v;
  }
  __syncthreads();

  int ty = tid >> 4;
  int tx = tid & 15;
  float4 acc4[4] = {make_float4(0,0,0,0), make_float4(0,0,0,0),
                    make_float4(0,0,0,0), make_float4(0,0,0,0)};
  int xsw = (ty & 3) << 1;

  #pragma unroll 2
  for (int k4 = 0; k4 < 32; ++k4){
    int kb = k4 * 4;
    int physoff = (k4 ^ xsw) * 4;
    float4 xv0 = *reinterpret_cast<const float4*>(&xs[(ty*4+0)*128 + physoff]);
    float4 xv1 = *reinterpret_cast<const float4*>(&xs[(ty*4+1)*128 + physoff]);
    float4 xv2 = *reinterpret_cast<const float4*>(&xs[(ty*4+2)*128 + physoff]);
    float4 xv3 = *reinterpret_cast<const float4*>(&xs[(ty*4+3)*128 + physoff]);
    float4 wv0 = *reinterpret_cast<const float4*>(&wk[(kb+0)*64 + tx*4]);
    float4 wv1 = *reinterpret_cast<const float4*>(&wk[(kb+1)*64 + tx*4]);
    float4 wv2 = *reinterpret_cast<const float4*>(&wk[(kb+2)*64 + tx*4]);
    float4 wv3 = *reinterpret_cast<const float4*>(&wk[(kb+3)*64 + tx*4]);
    fma4(acc4[0], xv0.x, wv0); fma4(acc4[0], xv0.y, wv1); fma4(acc4[0], xv0.z, wv2); fma4(acc4[0], xv0.w, wv3);
    fma4(acc4[1], xv1.x, wv0); fma4(acc4[1], xv1.y, wv1); fma4(acc4[1], xv1.z, wv2); fma4(acc4[1], xv1.w, wv3);
    fma4(acc4[2], xv2.x, wv0); fma4(acc4[2], xv2.y, wv1); fma4(acc4[2], xv2.z, wv2); fma4(acc4[2], xv2.w, wv3);
    fma4(acc4[3], xv3.x, wv0); fma4(acc4[3], xv3.y, wv1); fma4(acc4[3], xv3.z, wv2); fma4(acc4[3], xv3.w, wv3);
  }

  float4 b4 = *reinterpret_cast<const float4*>(bias + tx*4);
  #pragma unroll
  for (int i = 0; i < 4; ++i){
    int pp = base + ty*4 + i;
    if (pp < endp){
      int nid = nbt[pp];
      float4 o4 = make_float4(acc4[i].x + b4.x, acc4[i].y + b4.y,
                              acc4[i].z + b4.z, acc4[i].w + b4.w);
      *reinterpret_cast<float4*>(outp + (size_t)nid*128 + c0 + tx*4) = o4;
    }
  }
}

// ---------- 7: per-dst-node wave: LL walk, no-max softmax (|att|<=2.9), DPP reduce,
//               1-deep software pipeline; fused GELU + LayerNorm ----------
__global__ __launch_bounds__(256) void k_edge(const float* q, const float* k,
      const float* hs, const float* hn,
      const int* head, const int* nxt, const int* ei,
      const int* ntype,
      const float* rel_att, const float* rel_h_att,
      const float* ln_g, const float* ln_b,
      float* out, int N){
  int wid = (blockIdx.x*blockDim.x + threadIdx.x) >> 6;
  if (wid >= N) return;
  int lane = threadIdx.x & 63;
  int h = lane >> 3, t8 = lane & 7;
  const float2 qv = *reinterpret_cast<const float2*>(q + (size_t)wid*128 + lane*2);
  float hsv = hs[(size_t)wid*64 + lane];
  int st = ntype[wid];
  int rb = st*8 + h;
  float ra0 = rel_att[rb*16 + t8*2]     * 0.25f;                 // fold /sqrt(16)
  float ra1 = rel_att[rb*16 + t8*2 + 1] * 0.25f;
  float rha = rel_h_att[rb*8 + t8]      * 0.35355339059327373f;  // fold /sqrt(8)
  float s = 0.f, a0 = 0.f, a1 = 0.f;

  int e = head[wid];
  int en = -1; float2 kv = make_float2(0.f, 0.f); float hnv = 0.f;
  if (e >= 0){
    en = nxt[e];
    int sj = ei[e];
    kv  = *reinterpret_cast<const float2*>(k + (size_t)sj*128 + lane*2);
    hnv = hn[(size_t)sj*64 + lane];
  }
  while (e >= 0){
    int en2 = -1; float2 kv2 = kv; float hnv2 = hnv;
    if (en >= 0){
      en2 = nxt[en];
      int sj2 = ei[en];
      kv2  = *reinterpret_cast<const float2*>(k + (size_t)sj2*128 + lane*2);
      hnv2 = hn[(size_t)sj2*64 + lane];
    }
    float pp = tanh_fast(qv.x*kv.x)*ra0 + tanh_fast(qv.y*kv.y)*ra1;
    float ph = tanh_fast(hsv*hnv)*rha;
    pp = sum8(pp);
    ph = sum8(ph);
    float w = __expf(pp * ph);
    s += w;
    a0 = fmaf(w, kv.x, a0);
    a1 = fmaf(w, kv.y, a1);
    e = en; en = en2; kv = kv2; hnv = hnv2;
  }
  float inv = 1.0f / (s + 1e-16f);
  float x0 = a0*inv, x1 = a1*inv;
  x0 = 0.5f * x0 * (1.f + erff(x0 * 0.70710678118654752f));
  x1 = 0.5f * x1 * (1.f + erff(x1 * 0.70710678118654752f));
  float sm = x0 + x1, sq = x0*x0 + x1*x1;
  #pragma unroll
  for (int d = 1; d < 64; d <<= 1){ sm += __shfl_xor(sm, d); sq += __shfl_xor(sq, d); }
  float mu = sm * (1.f/128.f);
  float var = fmaxf(sq * (1.f/128.f) - mu*mu, 0.f);
  float r = rsqrtf(var + 1e-5f);
  float g0 = ln_g[lane*2],  g1 = ln_g[lane*2+1];
  float be0 = ln_b[lane*2], be1 = ln_b[lane*2+1];
  float2 o2 = make_float2((x0 - mu)*r*g0 + be0, (x1 - mu)*r*g1 + be1);
  *reinterpret_cast<float2*>(out + (size_t)wid*128 + lane*2) = o2;
}

extern "C" void kernel_launch(void* const* d_in, const int* in_sizes, int n_in,
                              void* d_out, int out_size, void* d_ws, size_t ws_size,
                              hipStream_t stream) {
  const float* meta_xs  = (const float*)d_in[0];
  const int*   node_type= (const int*)d_in[1];
  const int*   edge_idx = (const int*)d_in[2];
  const float* h_mat    = (const float*)d_in[3];
  const float* sub_W    = (const float*)d_in[4];
  const float* sub_b    = (const float*)d_in[5];
  const float* neigh_W  = (const float*)d_in[6];
  const float* neigh_b  = (const float*)d_in[7];
  const float* hsub_W   = (const float*)d_in[8];
  const float* hsub_b   = (const float*)d_in[9];
  const float* hneigh_W = (const float*)d_in[10];
  const float* hneigh_b = (const float*)d_in[11];
  const float* rel_att  = (const float*)d_in[12];
  const float* rel_hatt = (const float*)d_in[13];
  const float* ln_g     = (const float*)d_in[14];
  const float* ln_b     = (const float*)d_in[15];

  const int N = in_sizes[0] / 128;
  const int E = in_sizes[2] / 2;

  char* wbase = (char*)d_ws;
  size_t o = 0;
  auto carve = [&](size_t bytes)->char* {
    char* p = wbase + o;
    o = (o + bytes + 255) & ~(size_t)255;
    return p;
  };
  float* q      = (float*)carve((size_t)N*128*4);
  float* k      = (float*)carve((size_t)N*128*4);
  float* hs     = (float*)carve((size_t)N*64*4);
  float* hn     = (float*)carve((size_t)N*64*4);
  int*   head   = (int*)carve((size_t)N*4);
  int*   nxt    = (int*)carve((size_t)E*4);
  int*   nbt    = (int*)carve((size_t)N*4);
  int*   tmeta  = (int*)carve(64);
  if (o > ws_size) return;

  int* tcnt = tmeta;
  int* toff = tmeta + 4;
  int* tcur = tmeta + 9;

  k_init   <<<(N+255)/256, 256, 0, stream>>>(head, tmeta, N);
  k_tc     <<<(N+255)/256, 256, 0, stream>>>(node_type, tcnt, N);
  k_toff   <<<1, 64, 0, stream>>>(tcnt, toff, tcur);
  k_nbt    <<<(N+255)/256, 256, 0, stream>>>(node_type, tcur, nbt, N);
  k_ll     <<<(E+255)/256, 256, 0, stream>>>(edge_idx, head, nxt, E);
  k_h      <<<((size_t)N*64+255)/256, 256, 0, stream>>>(h_mat, hsub_W, hsub_b,
                                                        hneigh_W, hneigh_b, hs, hn, N);
  dim3 g_qk(((N + 63) >> 6) + 4, 4);
  k_qk_gemm<<<g_qk, 256, 0, stream>>>(meta_xs, sub_W, neigh_W, sub_b, neigh_b,
                                      nbt, toff, q, k);
  k_edge   <<<(N+3)/4, 256, 0, stream>>>(q, k, hs, hn, head, nxt, edge_idx, node_type,
                                         rel_att, rel_hatt, ln_g, ln_b,
                                         (float*)d_out, N);
}

// Round 11
// 381.961 us; speedup vs baseline: 4.5015x; 1.0654x over previous
//
#include <hip/hip_runtime.h>

__device__ __forceinline__ float tanh_fast(float x){
  float e = __expf(2.0f * x);
  return 1.0f - 2.0f * __builtin_amdgcn_rcpf(e + 1.0f);
}
template<int CTRL>
__device__ __forceinline__ float dpp_add(float x){
  union { float f; int i; } a, b;
  a.f = x;
  b.i = __builtin_amdgcn_mov_dpp(a.i, CTRL, 0xF, 0xF, true);
  return x + b.f;
}
__device__ __forceinline__ float sum8(float x){
  x = dpp_add<0xB1>(x);    // quad_perm [1,0,3,2]
  x = dpp_add<0x4E>(x);    // quad_perm [2,3,0,1]
  x = dpp_add<0x141>(x);   // row_half_mirror
  return x;
}
__device__ __forceinline__ void fma4(float4& a, float s, const float4& b){
  a.x = fmaf(s, b.x, a.x); a.y = fmaf(s, b.y, a.y);
  a.z = fmaf(s, b.z, a.z); a.w = fmaf(s, b.w, a.w);
}
__device__ __forceinline__ unsigned int f2bf(float f){
  union { float ff; unsigned int i; } c; c.ff = f;
  return (c.i + 0x7FFFu + ((c.i >> 16) & 1u)) >> 16;
}
__device__ __forceinline__ float bf2f(unsigned int u){
  union { unsigned int i; float f; } c; c.i = u << 16; return c.f;
}

// ---------- 1: single-block type histogram + scan (no pre-zero needed) ----------
__global__ __launch_bounds__(1024) void k_types(const int* ntype, int* tmeta, int N){
  __shared__ int cnt[4];
  int tid = threadIdx.x;
  if (tid < 4) cnt[tid] = 0;
  __syncthreads();
  int c0=0,c1=0,c2=0,c3=0;
  for (int i = tid; i < N; i += 1024){
    int t = ntype[i];
    c0 += (t==0); c1 += (t==1); c2 += (t==2); c3 += (t==3);
  }
  if (c0) atomicAdd(&cnt[0], c0);
  if (c1) atomicAdd(&cnt[1], c1);
  if (c2) atomicAdd(&cnt[2], c2);
  if (c3) atomicAdd(&cnt[3], c3);
  __syncthreads();
  if (tid == 0){
    int a = 0;
    tmeta[4] = 0;                    // toff[0]
    for (int k = 0; k < 4; ++k){ tmeta[k] = cnt[k]; a += cnt[k]; tmeta[5+k] = a; }
    for (int k = 0; k < 4; ++k) tmeta[9+k] = tmeta[4+k];   // tcur = toff
  }
}

// ---------- 2: head init (padded: 1 line/dst) + node type-bucketing ----------
__global__ void k_init_nbt(const int* ntype, int* head, int* tcur, int* nbt, int N){
  int i = blockIdx.x*blockDim.x + threadIdx.x;
  if (i >= N) return;
  head[i << 4] = -1;
  int lane = threadIdx.x & 63;
  int myt = ntype[i];
  unsigned long long below = (lane == 0) ? 0ull : ((~0ull) >> (64 - lane));
  #pragma unroll
  for (int tt = 0; tt < 4; ++tt){
    unsigned long long mask = __ballot(myt == tt);
    if (mask){
      int leader = __ffsll((long long)mask) - 1;
      int base = 0;
      if (lane == leader) base = atomicAdd(&tcur[tt], __popcll(mask));
      base = __shfl(base, leader);
      if (myt == tt){
        int pos = base + __popcll(mask & below);
        nbt[pos] = i;
      }
    }
  }
}

// ---------- 3: fused [h projections | linked-list build] via block split ----------
__global__ void k_ll_h(const int* ei, int* head, int2* nsrc, int E,
                       const float* h_mat, const float* hsW, const float* hsb,
                       const float* hnW, const float* hnb,
                       float* hs, unsigned short* hn_pk, int N, int HB){
  int b = blockIdx.x;
  if (b < HB){
    int i = b*256 + threadIdx.x;
    if (i >= N*64) return;
    int n = i >> 6, c = i & 63;
    float a0 = 0.f, a1 = 0.f;
    const float* hm = h_mat + (size_t)n*8;
    #pragma unroll
    for (int d = 0; d < 8; ++d){
      float hv = hm[d];
      a0 += hv * hsW[d*64 + c];
      a1 += hv * hnW[d*64 + c];
    }
    hs[i] = a0 + hsb[c];
    hn_pk[i] = (unsigned short)f2bf(a1 + hnb[c]);
  } else {
    int i = (b - HB)*256 + threadIdx.x;
    if (i >= E) return;
    int d = ei[E + i];
    int s = ei[i];
    int old = atomicExch(&head[d << 4], i);
    nsrc[i] = make_int2(old, s);
  }
}

// ---------- 4: type-selected projections, tiled f32 GEMM; q f32, k packed bf16 ----------
__global__ __launch_bounds__(256) void k_qk_gemm(const float* X,
      const float* subW, const float* neighW,
      const float* sub_b, const float* neigh_b,
      const int* nbt, const int* toff,
      float* q, unsigned int* k_pk){
  int b = blockIdx.x;
  int t = -1, chunk = 0, acc0 = 0;
  #pragma unroll
  for (int tt = 0; tt < 4; ++tt){
    int cnt = toff[tt+1] - toff[tt];
    int nc = (cnt + 63) >> 6;
    if (t < 0 && b < acc0 + nc){ t = tt; chunk = b - acc0; }
    acc0 += nc;
  }
  if (t < 0) return;
  int base = toff[t] + chunk*64;
  int endp = toff[t+1];
  int fallback = toff[t];

  bool isK = blockIdx.y >= 2;
  int c0 = (blockIdx.y & 1) * 64;
  const float* Wg   = (isK ? neighW : subW) + ((size_t)t << 14);
  const float* bias = (isK ? neigh_b : sub_b) + t*128 + c0;

  __shared__ float xs[64*128];
  __shared__ float wk[128*64];

  int tid = threadIdx.x;
  #pragma unroll
  for (int i = 0; i < 8; ++i){
    int f = tid + i*256;
    int node = f >> 5;
    int f4 = f & 31;
    int pp = base + node;
    int nid = nbt[pp < endp ? pp : fallback];
    float4 v = *reinterpret_cast<const float4*>(X + (size_t)nid*128 + f4*4);
    int phys = f4 ^ (((node >> 2) & 3) << 1);
    *reinterpret_cast<float4*>(&xs[node*128 + phys*4]) = v;
  }
  #pragma unroll
  for (int i = 0; i < 8; ++i){
    int f = tid + i*256;
    int kk = f >> 4;
    int col = (f & 15) * 4;
    float4 v = *reinterpret_cast<const float4*>(Wg + (size_t)kk*128 + c0 + col);
    *reinterpret_cast<float4*>(&wk[kk*64 + col]) = v;
  }
  __syncthreads();

  int ty = tid >> 4;
  int tx = tid & 15;
  float4 acc4[4] = {make_float4(0,0,0,0), make_float4(0,0,0,0),
                    make_float4(0,0,0,0), make_float4(0,0,0,0)};
  int xsw = (ty & 3) << 1;

  #pragma unroll 2
  for (int k4 = 0; k4 < 32; ++k4){
    int kb = k4 * 4;
    int physoff = (k4 ^ xsw) * 4;
    float4 xv0 = *reinterpret_cast<const float4*>(&xs[(ty*4+0)*128 + physoff]);
    float4 xv1 = *reinterpret_cast<const float4*>(&xs[(ty*4+1)*128 + physoff]);
    float4 xv2 = *reinterpret_cast<const float4*>(&xs[(ty*4+2)*128 + physoff]);
    float4 xv3 = *reinterpret_cast<const float4*>(&xs[(ty*4+3)*128 + physoff]);
    float4 wv0 = *reinterpret_cast<const float4*>(&wk[(kb+0)*64 + tx*4]);
    float4 wv1 = *reinterpret_cast<const float4*>(&wk[(kb+1)*64 + tx*4]);
    float4 wv2 = *reinterpret_cast<const float4*>(&wk[(kb+2)*64 + tx*4]);
    float4 wv3 = *reinterpret_cast<const float4*>(&wk[(kb+3)*64 + tx*4]);
    fma4(acc4[0], xv0.x, wv0); fma4(acc4[0], xv0.y, wv1); fma4(acc4[0], xv0.z, wv2); fma4(acc4[0], xv0.w, wv3);
    fma4(acc4[1], xv1.x, wv0); fma4(acc4[1], xv1.y, wv1); fma4(acc4[1], xv1.z, wv2); fma4(acc4[1], xv1.w, wv3);
    fma4(acc4[2], xv2.x, wv0); fma4(acc4[2], xv2.y, wv1); fma4(acc4[2], xv2.z, wv2); fma4(acc4[2], xv2.w, wv3);
    fma4(acc4[3], xv3.x, wv0); fma4(acc4[3], xv3.y, wv1); fma4(acc4[3], xv3.z, wv2); fma4(acc4[3], xv3.w, wv3);
  }

  float4 b4 = *reinterpret_cast<const float4*>(bias + tx*4);
  #pragma unroll
  for (int i = 0; i < 4; ++i){
    int pp = base + ty*4 + i;
    if (pp < endp){
      int nid = nbt[pp];
      float4 o4 = make_float4(acc4[i].x + b4.x, acc4[i].y + b4.y,
                              acc4[i].z + b4.z, acc4[i].w + b4.w);
      if (!isK){
        *reinterpret_cast<float4*>(q + (size_t)nid*128 + c0 + tx*4) = o4;
      } else {
        uint2 pk;
        pk.x = (f2bf(o4.y) << 16) | f2bf(o4.x);
        pk.y = (f2bf(o4.w) << 16) | f2bf(o4.z);
        *reinterpret_cast<uint2*>(k_pk + (size_t)nid*64 + (c0 >> 1) + tx*2) = pk;
      }
    }
  }
}

// ---------- 5: per-dst-node wave: LL walk (fused next+src), packed-bf16 gathers,
//               no-max softmax, DPP reduce, fused GELU + LayerNorm ----------
__global__ __launch_bounds__(256) void k_edge(const float* q, const unsigned int* k_pk,
      const float* hs, const unsigned short* hn_pk,
      const int* head, const int2* nsrc,
      const int* ntype,
      const float* rel_att, const float* rel_h_att,
      const float* ln_g, const float* ln_b,
      float* out, int N){
  int wid = (blockIdx.x*blockDim.x + threadIdx.x) >> 6;
  if (wid >= N) return;
  int lane = threadIdx.x & 63;
  int h = lane >> 3, t8 = lane & 7;
  const float2 qv = *reinterpret_cast<const float2*>(q + (size_t)wid*128 + lane*2);
  float hsv = hs[(size_t)wid*64 + lane];
  int st = ntype[wid];
  int rb = st*8 + h;
  float ra0 = rel_att[rb*16 + t8*2]     * 0.25f;
  float ra1 = rel_att[rb*16 + t8*2 + 1] * 0.25f;
  float rha = rel_h_att[rb*8 + t8]      * 0.35355339059327373f;
  float s = 0.f, a0 = 0.f, a1 = 0.f;

  int e = head[wid << 4];
  int en = -1;
  unsigned int kp = 0; unsigned int hp = 0;
  if (e >= 0){
    int2 ns = nsrc[e];
    en = ns.x;
    kp = k_pk[(size_t)ns.y*64 + lane];
    hp = hn_pk[(size_t)ns.y*64 + lane];
  }
  while (e >= 0){
    int en2 = -1;
    unsigned int kp2 = kp, hp2 = hp;
    if (en >= 0){
      int2 ns = nsrc[en];
      en2 = ns.x;
      kp2 = k_pk[(size_t)ns.y*64 + lane];
      hp2 = hn_pk[(size_t)ns.y*64 + lane];
    }
    float kx = bf2f(kp & 0xffffu), ky = bf2f(kp >> 16), hnv = bf2f(hp);
    float pp = tanh_fast(qv.x*kx)*ra0 + tanh_fast(qv.y*ky)*ra1;
    float ph = tanh_fast(hsv*hnv)*rha;
    pp = sum8(pp);
    ph = sum8(ph);
    float w = __expf(pp * ph);
    s += w;
    a0 = fmaf(w, kx, a0);
    a1 = fmaf(w, ky, a1);
    e = en; en = en2; kp = kp2; hp = hp2;
  }
  float inv = 1.0f / (s + 1e-16f);
  float x0 = a0*inv, x1 = a1*inv;
  x0 = 0.5f * x0 * (1.f + erff(x0 * 0.70710678118654752f));
  x1 = 0.5f * x1 * (1.f + erff(x1 * 0.70710678118654752f));
  float sm = x0 + x1, sq = x0*x0 + x1*x1;
  #pragma unroll
  for (int d = 1; d < 64; d <<= 1){ sm += __shfl_xor(sm, d); sq += __shfl_xor(sq, d); }
  float mu = sm * (1.f/128.f);
  float var = fmaxf(sq * (1.f/128.f) - mu*mu, 0.f);
  float r = rsqrtf(var + 1e-5f);
  float g0 = ln_g[lane*2],  g1 = ln_g[lane*2+1];
  float be0 = ln_b[lane*2], be1 = ln_b[lane*2+1];
  float2 o2 = make_float2((x0 - mu)*r*g0 + be0, (x1 - mu)*r*g1 + be1);
  *reinterpret_cast<float2*>(out + (size_t)wid*128 + lane*2) = o2;
}

extern "C" void kernel_launch(void* const* d_in, const int* in_sizes, int n_in,
                              void* d_out, int out_size, void* d_ws, size_t ws_size,
                              hipStream_t stream) {
  const float* meta_xs  = (const float*)d_in[0];
  const int*   node_type= (const int*)d_in[1];
  const int*   edge_idx = (const int*)d_in[2];
  const float* h_mat    = (const float*)d_in[3];
  const float* sub_W    = (const float*)d_in[4];
  const float* sub_b    = (const float*)d_in[5];
  const float* neigh_W  = (const float*)d_in[6];
  const float* neigh_b  = (const float*)d_in[7];
  const float* hsub_W   = (const float*)d_in[8];
  const float* hsub_b   = (const float*)d_in[9];
  const float* hneigh_W = (const float*)d_in[10];
  const float* hneigh_b = (const float*)d_in[11];
  const float* rel_att  = (const float*)d_in[12];
  const float* rel_hatt = (const float*)d_in[13];
  const float* ln_g     = (const float*)d_in[14];
  const float* ln_b     = (const float*)d_in[15];

  const int N = in_sizes[0] / 128;
  const int E = in_sizes[2] / 2;

  char* wbase = (char*)d_ws;
  size_t o = 0;
  auto carve = [&](size_t bytes)->char* {
    char* p = wbase + o;
    o = (o + bytes + 255) & ~(size_t)255;
    return p;
  };
  float*          q     = (float*)carve((size_t)N*128*4);
  unsigned int*   k_pk  = (unsigned int*)carve((size_t)N*64*4);
  float*          hs    = (float*)carve((size_t)N*64*4);
  unsigned short* hn_pk = (unsigned short*)carve((size_t)N*64*2);
  int*            head  = (int*)carve((size_t)N*16*4);   // 1 cache line per dst
  int2*           nsrc  = (int2*)carve((size_t)E*8);
  int*            nbt   = (int*)carve((size_t)N*4);
  int*            tmeta = (int*)carve(64);
  if (o > ws_size) return;

  int* toff = tmeta + 4;
  int* tcur = tmeta + 9;

  const int HB = (N*64 + 255) / 256;   // h-projection blocks in fused kernel
  const int LB = (E + 255) / 256;      // ll blocks

  k_types   <<<1, 1024, 0, stream>>>(node_type, tmeta, N);
  k_init_nbt<<<(N+255)/256, 256, 0, stream>>>(node_type, head, tcur, nbt, N);
  k_ll_h    <<<HB + LB, 256, 0, stream>>>(edge_idx, head, nsrc, E,
                                          h_mat, hsub_W, hsub_b, hneigh_W, hneigh_b,
                                          hs, hn_pk, N, HB);
  dim3 g_qk(((N + 63) >> 6) + 4, 4);
  k_qk_gemm <<<g_qk, 256, 0, stream>>>(meta_xs, sub_W, neigh_W, sub_b, neigh_b,
                                       nbt, toff, q, k_pk);
  k_edge    <<<(N+3)/4, 256, 0, stream>>>(q, k_pk, hs, hn_pk, head, nsrc, node_type,
                                          rel_att, rel_hatt, ln_g, ln_b,
                                          (float*)d_out, N);
}

// Round 12
// 356.718 us; speedup vs baseline: 4.8200x; 1.0708x over previous
//
#include <hip/hip_runtime.h>

typedef __bf16 bf16x8 __attribute__((ext_vector_type(8)));
typedef float f32x4 __attribute__((ext_vector_type(4)));

__device__ __forceinline__ float tanh_fast(float x){
  float e = __expf(2.0f * x);
  return 1.0f - 2.0f * __builtin_amdgcn_rcpf(e + 1.0f);
}
template<int CTRL>
__device__ __forceinline__ float dpp_add(float x){
  union { float f; int i; } a, b;
  a.f = x;
  b.i = __builtin_amdgcn_mov_dpp(a.i, CTRL, 0xF, 0xF, true);
  return x + b.f;
}
__device__ __forceinline__ float sum8(float x){
  x = dpp_add<0xB1>(x);    // quad_perm [1,0,3,2]
  x = dpp_add<0x4E>(x);    // quad_perm [2,3,0,1]
  x = dpp_add<0x141>(x);   // row_half_mirror
  return x;
}
__device__ __forceinline__ unsigned int f2bf(float f){
  union { float ff; unsigned int i; } c; c.ff = f;
  return (c.i + 0x7FFFu + ((c.i >> 16) & 1u)) >> 16;
}
__device__ __forceinline__ float bf2f(unsigned int u){
  union { unsigned int i; float f; } c; c.i = u << 16; return c.f;
}
__device__ __forceinline__ bf16x8 ld_bf8(const unsigned short* p){
  union { uint4 u; bf16x8 v; } c;
  c.u = *reinterpret_cast<const uint4*>(p);
  return c.v;
}
__device__ __forceinline__ bf16x8 ld_f32_to_bf8(const float* p){
  float4 lo = *reinterpret_cast<const float4*>(p);
  float4 hi = *reinterpret_cast<const float4*>(p + 4);
  union { unsigned short s[8]; bf16x8 v; } c;
  c.s[0]=f2bf(lo.x); c.s[1]=f2bf(lo.y); c.s[2]=f2bf(lo.z); c.s[3]=f2bf(lo.w);
  c.s[4]=f2bf(hi.x); c.s[5]=f2bf(hi.y); c.s[6]=f2bf(hi.z); c.s[7]=f2bf(hi.w);
  return c.v;
}

// ---------- 1: single-block type histogram + scan ----------
__global__ __launch_bounds__(1024) void k_types(const int* ntype, int* tmeta, int N){
  __shared__ int cnt[4];
  int tid = threadIdx.x;
  if (tid < 4) cnt[tid] = 0;
  __syncthreads();
  int c0=0,c1=0,c2=0,c3=0;
  for (int i = tid; i < N; i += 1024){
    int t = ntype[i];
    c0 += (t==0); c1 += (t==1); c2 += (t==2); c3 += (t==3);
  }
  if (c0) atomicAdd(&cnt[0], c0);
  if (c1) atomicAdd(&cnt[1], c1);
  if (c2) atomicAdd(&cnt[2], c2);
  if (c3) atomicAdd(&cnt[3], c3);
  __syncthreads();
  if (tid == 0){
    int a = 0;
    tmeta[4] = 0;
    for (int k = 0; k < 4; ++k){ tmeta[k] = cnt[k]; a += cnt[k]; tmeta[5+k] = a; }
    for (int k = 0; k < 4; ++k) tmeta[9+k] = tmeta[4+k];
  }
}

// ---------- 2: head init (padded) + node type-bucketing ----------
__global__ void k_init_nbt(const int* ntype, int* head, int* tcur, int* nbt, int N){
  int i = blockIdx.x*blockDim.x + threadIdx.x;
  if (i >= N) return;
  head[i << 4] = -1;
  int lane = threadIdx.x & 63;
  int myt = ntype[i];
  unsigned long long below = (lane == 0) ? 0ull : ((~0ull) >> (64 - lane));
  #pragma unroll
  for (int tt = 0; tt < 4; ++tt){
    unsigned long long mask = __ballot(myt == tt);
    if (mask){
      int leader = __ffsll((long long)mask) - 1;
      int base = 0;
      if (lane == leader) base = atomicAdd(&tcur[tt], __popcll(mask));
      base = __shfl(base, leader);
      if (myt == tt){
        int pos = base + __popcll(mask & below);
        nbt[pos] = i;
      }
    }
  }
}

// ---------- 3: fused [h proj | LL build | W transpose->bf16] via block ranges ----------
__global__ void k_ll_h_w(const int* ei, int* head, int2* nsrc, int E,
                         const float* h_mat, const float* hsW, const float* hsb,
                         const float* hnW, const float* hnb,
                         float* hs, unsigned short* hn_pk, int N, int HB, int LB,
                         const float* subW, const float* neighW,
                         unsigned short* wts, unsigned short* wtn){
  int b = blockIdx.x;
  if (b < HB){
    int i = b*256 + threadIdx.x;
    if (i >= N*64) return;
    int n = i >> 6, c = i & 63;
    float a0 = 0.f, a1 = 0.f;
    const float* hm = h_mat + (size_t)n*8;
    #pragma unroll
    for (int d = 0; d < 8; ++d){
      float hv = hm[d];
      a0 += hv * hsW[d*64 + c];
      a1 += hv * hnW[d*64 + c];
    }
    hs[i] = a0 + hsb[c];
    hn_pk[i] = (unsigned short)f2bf(a1 + hnb[c]);
  } else if (b < HB + LB){
    int i = (b - HB)*256 + threadIdx.x;
    if (i >= E) return;
    int d = ei[E + i];
    int s = ei[i];
    int old = atomicExch(&head[d << 4], i);
    nsrc[i] = make_int2(old, s);
  } else {
    int i = (b - HB - LB)*256 + threadIdx.x;   // 0 .. 131071
    int w = i >> 16;
    int r = i & 65535;
    int t = r >> 14;
    int rem = r & 16383;
    int o = rem >> 7;
    int kd = rem & 127;
    const float* src = w ? neighW : subW;
    unsigned short* dstp = w ? wtn : wts;
    dstp[(t << 14) + (o << 7) + kd] = (unsigned short)f2bf(src[(t << 14) + (kd << 7) + o]);
  }
}

// ---------- 4: type-selected projections via MFMA 16x16x32 bf16 (no LDS) ----------
// A frag: A[m=lane&15][k=quad*8+j]; B frag: B[k=quad*8+j][n=lane&15]
// C/D:    col = lane&15, row = quad*4 + reg      [guide §3, m89-verified]
__global__ __launch_bounds__(256) void k_qk_mfma(const float* X,
      const unsigned short* wts, const unsigned short* wtn,   // bf16 [t][o][k]
      const float* sub_b, const float* neigh_b,
      const int* nbt, const int* toff,
      float* q, unsigned short* k_pkS){
  int b = blockIdx.x;
  int t = -1, chunk = 0, acc = 0;
  #pragma unroll
  for (int tt = 0; tt < 4; ++tt){
    int cnt = toff[tt+1] - toff[tt];
    int nc = (cnt + 63) >> 6;
    if (t < 0 && b < acc + nc){ t = tt; chunk = b - acc; }
    acc += nc;
  }
  if (t < 0) return;
  int lane = threadIdx.x & 63;
  int w = threadIdx.x >> 6;
  int quad = lane >> 4, l16 = lane & 15;
  int base = toff[t] + chunk*64 + w*16;
  int endp = toff[t+1];
  int p = base + l16;
  int nid = nbt[p < endp ? p : toff[t]];
  bf16x8 a[4];
  #pragma unroll
  for (int kk = 0; kk < 4; ++kk)
    a[kk] = ld_f32_to_bf8(X + (size_t)nid*128 + kk*32 + quad*8);
  #pragma unroll
  for (int pj = 0; pj < 2; ++pj){
    const unsigned short* Wt = pj ? wtn : wts;
    const float* bias = pj ? neigh_b : sub_b;
    #pragma unroll
    for (int ot = 0; ot < 8; ++ot){
      int o = ot*16 + l16;
      f32x4 c = {0.f, 0.f, 0.f, 0.f};
      #pragma unroll
      for (int kk = 0; kk < 4; ++kk){
        bf16x8 bfr = ld_bf8(Wt + ((size_t)t << 14) + ((size_t)o << 7) + kk*32 + quad*8);
        c = __builtin_amdgcn_mfma_f32_16x16x32_bf16(a[kk], bfr, c, 0, 0, 0);
      }
      float bv = bias[t*128 + o];
      #pragma unroll
      for (int reg = 0; reg < 4; ++reg){
        int row = quad*4 + reg;
        int pp = base + row;
        if (pp < endp){
          int nid2 = nbt[pp];
          float v = c[reg] + bv;
          if (pj == 0) q[(size_t)nid2*128 + o] = v;
          else         k_pkS[(size_t)nid2*128 + o] = (unsigned short)f2bf(v);
        }
      }
    }
  }
}

// ---------- 5: per-dst-node wave: LL walk, 2-deep pipeline, packed-bf16 gathers,
//               no-max softmax, DPP reduce, fused GELU + LayerNorm ----------
__global__ __launch_bounds__(256) void k_edge(const float* q, const unsigned int* k_pk,
      const float* hs, const unsigned short* hn_pk,
      const int* head, const int2* nsrc,
      const int* ntype,
      const float* rel_att, const float* rel_h_att,
      const float* ln_g, const float* ln_b,
      float* out, int N){
  int wid = (blockIdx.x*blockDim.x + threadIdx.x) >> 6;
  if (wid >= N) return;
  int lane = threadIdx.x & 63;
  int h = lane >> 3, t8 = lane & 7;
  const float2 qv = *reinterpret_cast<const float2*>(q + (size_t)wid*128 + lane*2);
  float hsv = hs[(size_t)wid*64 + lane];
  int st = ntype[wid];
  int rb = st*8 + h;
  float ra0 = rel_att[rb*16 + t8*2]     * 0.25f;
  float ra1 = rel_att[rb*16 + t8*2 + 1] * 0.25f;
  float rha = rel_h_att[rb*8 + t8]      * 0.35355339059327373f;
  float s = 0.f, a0 = 0.f, a1 = 0.f;

  // 2-deep software pipeline over the linked list
  int ea = head[wid << 4];
  int eb = -1, ec = -1;
  unsigned int kpa = 0, hpa = 0, kpb = 0, hpb = 0;
  if (ea >= 0){
    int2 ns = nsrc[ea]; eb = ns.x;
    kpa = k_pk[(size_t)ns.y*64 + lane];
    hpa = hn_pk[(size_t)ns.y*64 + lane];
  }
  if (eb >= 0){
    int2 ns = nsrc[eb]; ec = ns.x;
    kpb = k_pk[(size_t)ns.y*64 + lane];
    hpb = hn_pk[(size_t)ns.y*64 + lane];
  }
  while (ea >= 0){
    int ed = -1; unsigned int kpc = 0, hpc = 0;
    if (ec >= 0){
      int2 ns = nsrc[ec]; ed = ns.x;
      kpc = k_pk[(size_t)ns.y*64 + lane];
      hpc = hn_pk[(size_t)ns.y*64 + lane];
    }
    float kx = bf2f(kpa & 0xffffu), ky = bf2f(kpa >> 16), hnv = bf2f(hpa);
    float pp = tanh_fast(qv.x*kx)*ra0 + tanh_fast(qv.y*ky)*ra1;
    float ph = tanh_fast(hsv*hnv)*rha;
    pp = sum8(pp);
    ph = sum8(ph);
    float w = __expf(pp * ph);
    s += w;
    a0 = fmaf(w, kx, a0);
    a1 = fmaf(w, ky, a1);
    ea = eb; eb = ec; ec = ed;
    kpa = kpb; kpb = kpc; hpa = hpb; hpb = hpc;
  }
  float inv = 1.0f / (s + 1e-16f);
  float x0 = a0*inv, x1 = a1*inv;
  x0 = 0.5f * x0 * (1.f + erff(x0 * 0.70710678118654752f));
  x1 = 0.5f * x1 * (1.f + erff(x1 * 0.70710678118654752f));
  float sm = x0 + x1, sq = x0*x0 + x1*x1;
  #pragma unroll
  for (int d = 1; d < 64; d <<= 1){ sm += __shfl_xor(sm, d); sq += __shfl_xor(sq, d); }
  float mu = sm * (1.f/128.f);
  float var = fmaxf(sq * (1.f/128.f) - mu*mu, 0.f);
  float r = rsqrtf(var + 1e-5f);
  float g0 = ln_g[lane*2],  g1 = ln_g[lane*2+1];
  float be0 = ln_b[lane*2], be1 = ln_b[lane*2+1];
  float2 o2 = make_float2((x0 - mu)*r*g0 + be0, (x1 - mu)*r*g1 + be1);
  *reinterpret_cast<float2*>(out + (size_t)wid*128 + lane*2) = o2;
}

extern "C" void kernel_launch(void* const* d_in, const int* in_sizes, int n_in,
                              void* d_out, int out_size, void* d_ws, size_t ws_size,
                              hipStream_t stream) {
  const float* meta_xs  = (const float*)d_in[0];
  const int*   node_type= (const int*)d_in[1];
  const int*   edge_idx = (const int*)d_in[2];
  const float* h_mat    = (const float*)d_in[3];
  const float* sub_W    = (const float*)d_in[4];
  const float* sub_b    = (const float*)d_in[5];
  const float* neigh_W  = (const float*)d_in[6];
  const float* neigh_b  = (const float*)d_in[7];
  const float* hsub_W   = (const float*)d_in[8];
  const float* hsub_b   = (const float*)d_in[9];
  const float* hneigh_W = (const float*)d_in[10];
  const float* hneigh_b = (const float*)d_in[11];
  const float* rel_att  = (const float*)d_in[12];
  const float* rel_hatt = (const float*)d_in[13];
  const float* ln_g     = (const float*)d_in[14];
  const float* ln_b     = (const float*)d_in[15];

  const int N = in_sizes[0] / 128;
  const int E = in_sizes[2] / 2;

  char* wbase = (char*)d_ws;
  size_t o = 0;
  auto carve = [&](size_t bytes)->char* {
    char* p = wbase + o;
    o = (o + bytes + 255) & ~(size_t)255;
    return p;
  };
  float*          q     = (float*)carve((size_t)N*128*4);
  unsigned int*   k_pk  = (unsigned int*)carve((size_t)N*64*4);   // = ushort[N*128]
  float*          hs    = (float*)carve((size_t)N*64*4);
  unsigned short* hn_pk = (unsigned short*)carve((size_t)N*64*2);
  int*            head  = (int*)carve((size_t)N*16*4);
  int2*           nsrc  = (int2*)carve((size_t)E*8);
  int*            nbt   = (int*)carve((size_t)N*4);
  int*            tmeta = (int*)carve(64);
  unsigned short* wts   = (unsigned short*)carve((size_t)4*128*128*2);
  unsigned short* wtn   = (unsigned short*)carve((size_t)4*128*128*2);
  if (o > ws_size) return;

  int* toff = tmeta + 4;
  int* tcur = tmeta + 9;

  const int HB = (N*64 + 255) / 256;
  const int LB = (E + 255) / 256;
  const int WB = (2*4*128*128) / 256;   // 512

  k_types   <<<1, 1024, 0, stream>>>(node_type, tmeta, N);
  k_init_nbt<<<(N+255)/256, 256, 0, stream>>>(node_type, head, tcur, nbt, N);
  k_ll_h_w  <<<HB + LB + WB, 256, 0, stream>>>(edge_idx, head, nsrc, E,
                                               h_mat, hsub_W, hsub_b, hneigh_W, hneigh_b,
                                               hs, hn_pk, N, HB, LB,
                                               sub_W, neigh_W, wts, wtn);
  k_qk_mfma <<<((N+63)>>6)+4, 256, 0, stream>>>(meta_xs, wts, wtn, sub_b, neigh_b,
                                                nbt, toff, q, (unsigned short*)k_pk);
  k_edge    <<<(N+3)/4, 256, 0, stream>>>(q, k_pk, hs, hn_pk, head, nsrc, node_type,
                                          rel_att, rel_hatt, ln_g, ln_b,
                                          (float*)d_out, N);
}